// Round 9
// baseline (442.448 us; speedup 1.0000x reference)
//
#include <hip/hip_runtime.h>
#include <cfloat>
#include <cstddef>

constexpr int KIN   = 128;
constexpr int KQD   = 32;
constexpr int KT    = 50;
constexpr int KLH   = 128;
constexpr float BN_EPS = 1e-5f;

typedef __attribute__((ext_vector_type(8))) short bf16x8;
typedef __attribute__((ext_vector_type(4))) float f32x4;
union U8 { bf16x8 v; unsigned u[4]; };

__device__ __forceinline__ float elu_f(float x)  { return x > 0.f ? x : expm1f(x); }
__device__ __forceinline__ float leaky_f(float x){ return x > 0.f ? x : 0.2f * x; }
__device__ __forceinline__ float fsigm(float x)  { return 1.f / (1.f + __expf(-x)); }
__device__ __forceinline__ float ftanh(float x)  { return 1.f - 2.f / (__expf(2.f * x) + 1.f); }

__device__ __forceinline__ unsigned bfpack(float lo, float hi) {
    unsigned ul = __float_as_uint(lo), uh = __float_as_uint(hi);
    ul += 0x7FFFu + ((ul >> 16) & 1u);
    uh += 0x7FFFu + ((uh >> 16) & 1u);
    return (ul >> 16) | (uh & 0xFFFF0000u);
}
__device__ __forceinline__ unsigned short bf1(float v) {
    unsigned u = __float_as_uint(v);
    u += 0x7FFFu + ((u >> 16) & 1u);
    return (unsigned short)(u >> 16);
}
__device__ __forceinline__ float bflo(unsigned u) { return __uint_as_float(u << 16); }
__device__ __forceinline__ float bfhi(unsigned u) { return __uint_as_float(u & 0xFFFF0000u); }

__device__ __forceinline__ bf16x8 pack8(float4 p, float4 q) {
    U8 t;
    t.u[0] = bfpack(p.x, p.y); t.u[1] = bfpack(p.z, p.w);
    t.u[2] = bfpack(q.x, q.y); t.u[3] = bfpack(q.z, q.w);
    return t.v;
}

// ---------------------------------------------------------------- K1: degree
__global__ void k_deg(const int* __restrict__ ei, int E, int* __restrict__ deg) {
    int e = blockIdx.x * blockDim.x + threadIdx.x;
    if (e < E) atomicAdd(&deg[ei[E + e]], 1);
}

// ---------------- K2a/b/c: hierarchical exclusive scan (parallel)
__global__ __launch_bounds__(1024)
void k_scan_a(const int* __restrict__ deg, int n, int* __restrict__ bsum) {
    __shared__ int wsum[16];
    int tid = threadIdx.x, lane = tid & 63, w = tid >> 6;
    int i0 = blockIdx.x * 4096 + tid * 4;
    int t = 0;
    #pragma unroll
    for (int j = 0; j < 4; j++) t += (i0 + j < n) ? deg[i0 + j] : 0;
    #pragma unroll
    for (int d = 1; d < 64; d <<= 1) t += __shfl_xor(t, d);
    if (lane == 0) wsum[w] = t;
    __syncthreads();
    if (tid == 0) {
        int s = 0;
        #pragma unroll
        for (int k = 0; k < 16; k++) s += wsum[k];
        bsum[blockIdx.x] = s;
    }
}

__global__ void k_scan_b(int* __restrict__ bsum, int nb) {
    if (threadIdx.x == 0) {
        int run = 0;
        for (int i = 0; i < nb; i++) { int v = bsum[i]; bsum[i] = run; run += v; }
    }
}

__global__ __launch_bounds__(1024)
void k_scan_c(const int* __restrict__ deg, int n, const int* __restrict__ bsum,
              int* __restrict__ offsets, int* __restrict__ cursor,
              float* __restrict__ dinv) {
    __shared__ int wsum[16];
    int tid = threadIdx.x, lane = tid & 63, w = tid >> 6;
    int i0 = blockIdx.x * 4096 + tid * 4;
    int v[4];
    #pragma unroll
    for (int j = 0; j < 4; j++) v[j] = (i0 + j < n) ? deg[i0 + j] : 0;
    int tsum = v[0] + v[1] + v[2] + v[3];
    int sc = tsum;
    #pragma unroll
    for (int d = 1; d < 64; d <<= 1) {
        int o = __shfl_up(sc, d);
        if (lane >= d) sc += o;
    }
    if (lane == 63) wsum[w] = sc;
    __syncthreads();
    if (w == 0) {
        int xx = (lane < 16) ? wsum[lane] : 0;
        #pragma unroll
        for (int d = 1; d < 16; d <<= 1) {
            int o = __shfl_up(xx, d);
            if (lane >= d) xx += o;
        }
        if (lane < 16) wsum[lane] = xx;
    }
    __syncthreads();
    int run = bsum[blockIdx.x] + ((w > 0) ? wsum[w - 1] : 0) + sc - tsum;
    #pragma unroll
    for (int j = 0; j < 4; j++) {
        int i = i0 + j;
        if (i < n) {
            cursor[i]      = run;
            offsets[i + 1] = run + v[j];
            dinv[i]        = rsqrtf((float)(v[j] + 1));
            run += v[j];
        }
    }
    if (blockIdx.x == 0 && tid == 0) offsets[0] = 0;
}

// ---------------------------------------------------------------- K3: fill
__global__ void k_fill(const int* __restrict__ ei, int E, int* __restrict__ cursor,
                       int* __restrict__ csr_src) {
    int e = blockIdx.x * blockDim.x + threadIdx.x;
    if (e < E) {
        int s = ei[e], d = ei[E + e];
        int pos = atomicAdd(&cursor[d], 1);
        csr_src[pos] = s;
    }
}

// ------------- K4/K6: MFMA bf16 GEMM  Y[r,:] = X[r,:] @ W,  128x128 weights
template <bool ATT>
__global__ __launch_bounds__(256, 4)
void k_gemm_mfma(const float* __restrict__ X, const float* __restrict__ W,
                 unsigned* __restrict__ Yb, int nrows,
                 const float* __restrict__ attS, const float* __restrict__ attD,
                 float* __restrict__ a_src, float* __restrict__ a_dst) {
    __shared__ float tile[16][132];
    __shared__ float as_sh[128], ad_sh[128];
    int tid  = threadIdx.x;
    int lane = tid & 63;
    int wv   = tid >> 6;
    if (ATT && tid < 128) { as_sh[tid] = attS[tid]; ad_sh[tid] = attD[tid]; }
    int l16 = lane & 15;
    int kq  = (lane >> 4) * 8;
    bf16x8 bfr[2][4];
    #pragma unroll
    for (int nt = 0; nt < 2; nt++) {
        int n = wv * 32 + nt * 16 + l16;
        #pragma unroll
        for (int kk = 0; kk < 4; kk++) {
            int k0 = kk * 32 + kq;
            float f[8];
            #pragma unroll
            for (int j = 0; j < 8; j++) f[j] = W[(size_t)(k0 + j) * 128 + n];
            U8 t;
            t.u[0] = bfpack(f[0], f[1]); t.u[1] = bfpack(f[2], f[3]);
            t.u[2] = bfpack(f[4], f[5]); t.u[3] = bfpack(f[6], f[7]);
            bfr[nt][kk] = t.v;
        }
    }
    int nch = (nrows + 15) / 16;
    for (int ch = blockIdx.x; ch < nch; ch += gridDim.x) {
        int r0 = ch * 16;
        int r  = r0 + l16;
        bool rok = r < nrows;
        const float* xr = X + (size_t)r * 128 + kq;
        float4 z4 = make_float4(0.f, 0.f, 0.f, 0.f);
        bf16x8 afr[4];
        #pragma unroll
        for (int kk = 0; kk < 4; kk++) {
            float4 p = rok ? *reinterpret_cast<const float4*>(xr + kk * 32)     : z4;
            float4 q = rok ? *reinterpret_cast<const float4*>(xr + kk * 32 + 4) : z4;
            afr[kk] = pack8(p, q);
        }
        f32x4 acc0 = {0.f, 0.f, 0.f, 0.f};
        f32x4 acc1 = {0.f, 0.f, 0.f, 0.f};
        #pragma unroll
        for (int kk = 0; kk < 4; kk++) {
            acc0 = __builtin_amdgcn_mfma_f32_16x16x32_bf16(afr[kk], bfr[0][kk], acc0, 0, 0, 0);
            acc1 = __builtin_amdgcn_mfma_f32_16x16x32_bf16(afr[kk], bfr[1][kk], acc1, 0, 0, 0);
        }
        __syncthreads();
        int rowb = (lane >> 4) * 4;
        int cb   = wv * 32 + l16;
        #pragma unroll
        for (int reg = 0; reg < 4; reg++) {
            tile[rowb + reg][cb]      = acc0[reg];
            tile[rowb + reg][cb + 16] = acc1[reg];
        }
        __syncthreads();
        #pragma unroll
        for (int i = 0; i < 4; i++) {
            int idx = tid + i * 256;
            int row = idx >> 6, cp = idx & 63;
            int rr = r0 + row;
            if (rr < nrows) {
                float2 f = *reinterpret_cast<const float2*>(&tile[row][cp * 2]);
                Yb[(size_t)rr * 64 + cp] = bfpack(f.x, f.y);
            }
        }
        if (ATT && tid < 64) {
            int rr2 = tid >> 2, h = tid & 3;
            if (r0 + rr2 < nrows) {
                float ps = 0.f, pd = 0.f;
                #pragma unroll
                for (int j = 0; j < 32; j++) {
                    float v = tile[rr2][h * 32 + j];
                    ps += v * as_sh[h * 32 + j];
                    pd += v * ad_sh[h * 32 + j];
                }
                a_src[(size_t)(r0 + rr2) * 4 + h] = ps;
                a_dst[(size_t)(r0 + rr2) * 4 + h] = pd;
            }
        }
    }
}

// ---------- K5: GAT aggregate — wave/node, alpha in LDS, bf16-pair gather
__global__ __launch_bounds__(256)
void k_gat_agg(const int* __restrict__ offsets, const int* __restrict__ csr_src,
               const float* __restrict__ a_src, const float* __restrict__ a_dst,
               const unsigned* __restrict__ xwb, const float* __restrict__ bias,
               const float* __restrict__ g1, const float* __restrict__ b1,
               const float* __restrict__ mu1, const float* __restrict__ var1,
               float* __restrict__ hout, int n) {
    __shared__ int   src_sh[4][64];
    __shared__ float al_sh[4][4][64];
    int lane = threadIdx.x & 63;
    int wv   = threadIdx.x >> 6;
    int wid  = (blockIdx.x * blockDim.x + threadIdx.x) >> 6;
    int nw   = (gridDim.x * blockDim.x) >> 6;
    int hP   = lane >> 4;
    int c0 = lane * 2, c1 = c0 + 1;
    float bi0 = bias[c0], bi1 = bias[c1];
    float A0 = g1[c0] * rsqrtf(var1[c0] + BN_EPS);
    float A1 = g1[c1] * rsqrtf(var1[c1] + BN_EPS);
    float B0 = b1[c0] - mu1[c0] * A0;
    float B1 = b1[c1] - mu1[c1] * A1;
    for (int node = wid; node < n; node += nw) {
        int beg = offsets[node], end = offsets[node + 1];
        int rowlen = end - beg, total = rowlen + 1;
        float4 adv = *reinterpret_cast<const float4*>(&a_dst[(size_t)node * 4]);
        int sv = (lane < rowlen) ? csr_src[beg + lane] : node;
        float4 as4 = *reinterpret_cast<const float4*>(&a_src[(size_t)sv * 4]);
        float e0 = leaky_f(as4.x + adv.x), e1 = leaky_f(as4.y + adv.y);
        float e2 = leaky_f(as4.z + adv.z), e3 = leaky_f(as4.w + adv.w);
        float m[4] = {-FLT_MAX, -FLT_MAX, -FLT_MAX, -FLT_MAX};
        if (lane < total) { m[0] = e0; m[1] = e1; m[2] = e2; m[3] = e3; }
        for (int i = lane + 64; i < total; i += 64) {
            int src = (i < rowlen) ? csr_src[beg + i] : node;
            float4 a4 = *reinterpret_cast<const float4*>(&a_src[(size_t)src * 4]);
            m[0] = fmaxf(m[0], leaky_f(a4.x + adv.x));
            m[1] = fmaxf(m[1], leaky_f(a4.y + adv.y));
            m[2] = fmaxf(m[2], leaky_f(a4.z + adv.z));
            m[3] = fmaxf(m[3], leaky_f(a4.w + adv.w));
        }
        #pragma unroll
        for (int off = 32; off; off >>= 1) {
            #pragma unroll
            for (int h = 0; h < 4; h++) m[h] = fmaxf(m[h], __shfl_xor(m[h], off));
        }
        float ex[4] = {0.f, 0.f, 0.f, 0.f};
        if (lane < total) {
            ex[0] = expf(e0 - m[0]); ex[1] = expf(e1 - m[1]);
            ex[2] = expf(e2 - m[2]); ex[3] = expf(e3 - m[3]);
        }
        float s[4] = {ex[0], ex[1], ex[2], ex[3]};
        for (int i = lane + 64; i < total; i += 64) {
            int src = (i < rowlen) ? csr_src[beg + i] : node;
            float4 a4 = *reinterpret_cast<const float4*>(&a_src[(size_t)src * 4]);
            s[0] += expf(leaky_f(a4.x + adv.x) - m[0]);
            s[1] += expf(leaky_f(a4.y + adv.y) - m[1]);
            s[2] += expf(leaky_f(a4.z + adv.z) - m[2]);
            s[3] += expf(leaky_f(a4.w + adv.w) - m[3]);
        }
        #pragma unroll
        for (int off = 32; off; off >>= 1) {
            #pragma unroll
            for (int h = 0; h < 4; h++) s[h] += __shfl_xor(s[h], off);
        }
        float inv[4];
        #pragma unroll
        for (int h = 0; h < 4; h++) inv[h] = 1.f / (s[h] + 1e-16f);
        src_sh[wv][lane] = sv;
        #pragma unroll
        for (int h = 0; h < 4; h++) al_sh[wv][h][lane] = ex[h] * inv[h];
        __builtin_amdgcn_wave_barrier();
        float acc0 = 0.f, acc1 = 0.f;
        int cnt = min(total, 64);
        {
            int i = 0;
            for (; i + 4 <= cnt; i += 4) {
                int s0 = src_sh[wv][i],     s1 = src_sh[wv][i + 1];
                int s2 = src_sh[wv][i + 2], s3 = src_sh[wv][i + 3];
                float a0 = al_sh[wv][hP][i],     a1 = al_sh[wv][hP][i + 1];
                float a2 = al_sh[wv][hP][i + 2], a3 = al_sh[wv][hP][i + 3];
                unsigned u0 = xwb[(size_t)s0 * 64 + lane];
                unsigned u1 = xwb[(size_t)s1 * 64 + lane];
                unsigned u2 = xwb[(size_t)s2 * 64 + lane];
                unsigned u3 = xwb[(size_t)s3 * 64 + lane];
                acc0 += a0 * bflo(u0); acc1 += a0 * bfhi(u0);
                acc0 += a1 * bflo(u1); acc1 += a1 * bfhi(u1);
                acc0 += a2 * bflo(u2); acc1 += a2 * bfhi(u2);
                acc0 += a3 * bflo(u3); acc1 += a3 * bfhi(u3);
            }
            for (; i < cnt; i++) {
                int src  = src_sh[wv][i];
                float aP = al_sh[wv][hP][i];
                unsigned u = xwb[(size_t)src * 64 + lane];
                acc0 += aP * bflo(u);
                acc1 += aP * bfhi(u);
            }
        }
        for (int base = 64; base < total; base += 64) {
            __builtin_amdgcn_wave_barrier();
            int i = base + lane;
            int src2 = node;
            float a0v = 0.f, a1v = 0.f, a2v = 0.f, a3v = 0.f;
            if (i < total) {
                if (i < rowlen) src2 = csr_src[beg + i];
                float4 a4 = *reinterpret_cast<const float4*>(&a_src[(size_t)src2 * 4]);
                a0v = expf(leaky_f(a4.x + adv.x) - m[0]) * inv[0];
                a1v = expf(leaky_f(a4.y + adv.y) - m[1]) * inv[1];
                a2v = expf(leaky_f(a4.z + adv.z) - m[2]) * inv[2];
                a3v = expf(leaky_f(a4.w + adv.w) - m[3]) * inv[3];
            }
            src_sh[wv][lane] = src2;
            al_sh[wv][0][lane] = a0v; al_sh[wv][1][lane] = a1v;
            al_sh[wv][2][lane] = a2v; al_sh[wv][3][lane] = a3v;
            __builtin_amdgcn_wave_barrier();
            int cnt2 = min(total - base, 64);
            for (int j = 0; j < cnt2; j++) {
                int src  = src_sh[wv][j];
                float aP = al_sh[wv][hP][j];
                unsigned u = xwb[(size_t)src * 64 + lane];
                acc0 += aP * bflo(u);
                acc1 += aP * bfhi(u);
            }
        }
        __builtin_amdgcn_wave_barrier();
        float vA = elu_f(acc0 + bi0);
        float vB = elu_f(acc1 + bi1);
        vA = vA * A0 + B0;
        vB = vB * A1 + B1;
        *reinterpret_cast<float2*>(&hout[(size_t)node * 128 + c0]) =
            make_float2(vA, vB);
    }
}

// ---------- K7: GCN aggregate — wave/node, bf16-pair gather + gate dot
__global__ __launch_bounds__(256)
void k_gcn_agg(const int* __restrict__ offsets, const int* __restrict__ csr_src,
               const float* __restrict__ dinv, const unsigned* __restrict__ hwb,
               const float* __restrict__ bias,
               const float* __restrict__ g2, const float* __restrict__ b2,
               const float* __restrict__ mu2, const float* __restrict__ var2,
               const float* __restrict__ gateW, const float* __restrict__ gateB,
               float* __restrict__ h2, float* __restrict__ gate, int n) {
    __shared__ int   src_sh[4][64];
    __shared__ float w_sh[4][64];
    int lane = threadIdx.x & 63;
    int wv   = threadIdx.x >> 6;
    int wid  = (blockIdx.x * blockDim.x + threadIdx.x) >> 6;
    int nw   = (gridDim.x * blockDim.x) >> 6;
    int c0 = lane * 2, c1 = c0 + 1;
    float bi0 = bias[c0], bi1 = bias[c1];
    float A0 = g2[c0] * rsqrtf(var2[c0] + BN_EPS);
    float A1 = g2[c1] * rsqrtf(var2[c1] + BN_EPS);
    float B0 = b2[c0] - mu2[c0] * A0;
    float B1 = b2[c1] - mu2[c1] * A1;
    float gw0 = gateW[c0], gw1 = gateW[c1], gB = gateB[0];
    for (int node = wid; node < n; node += nw) {
        int beg = offsets[node], end = offsets[node + 1];
        int rowlen = end - beg;
        float dn = dinv[node];
        unsigned us = hwb[(size_t)node * 64 + lane];
        float acc0 = dn * dn * bflo(us);
        float acc1 = dn * dn * bfhi(us);
        for (int base = 0; base < rowlen; base += 64) {
            __builtin_amdgcn_wave_barrier();
            int i = base + lane;
            int src2 = node;
            float wv2 = 0.f;
            if (i < rowlen) { src2 = csr_src[beg + i]; wv2 = dinv[src2] * dn; }
            src_sh[wv][lane] = src2;
            w_sh[wv][lane]   = wv2;
            __builtin_amdgcn_wave_barrier();
            int cnt = min(rowlen - base, 64);
            int j = 0;
            for (; j + 4 <= cnt; j += 4) {
                int s0 = src_sh[wv][j],     s1 = src_sh[wv][j + 1];
                int s2 = src_sh[wv][j + 2], s3 = src_sh[wv][j + 3];
                float w0 = w_sh[wv][j],     w1 = w_sh[wv][j + 1];
                float w2 = w_sh[wv][j + 2], w3 = w_sh[wv][j + 3];
                unsigned u0 = hwb[(size_t)s0 * 64 + lane];
                unsigned u1 = hwb[(size_t)s1 * 64 + lane];
                unsigned u2 = hwb[(size_t)s2 * 64 + lane];
                unsigned u3 = hwb[(size_t)s3 * 64 + lane];
                acc0 += w0 * bflo(u0); acc1 += w0 * bfhi(u0);
                acc0 += w1 * bflo(u1); acc1 += w1 * bfhi(u1);
                acc0 += w2 * bflo(u2); acc1 += w2 * bfhi(u2);
                acc0 += w3 * bflo(u3); acc1 += w3 * bfhi(u3);
            }
            for (; j < cnt; j++) {
                int src = src_sh[wv][j];
                float w = w_sh[wv][j];
                unsigned u = hwb[(size_t)src * 64 + lane];
                acc0 += w * bflo(u);
                acc1 += w * bfhi(u);
            }
        }
        __builtin_amdgcn_wave_barrier();
        float vA = elu_f(acc0 + bi0);
        float vB = elu_f(acc1 + bi1);
        vA = vA * A0 + B0;
        vB = vB * A1 + B1;
        *reinterpret_cast<float2*>(&h2[(size_t)node * 128 + c0]) =
            make_float2(vA, vB);
        float p = vA * gw0 + vB * gw1;
        #pragma unroll
        for (int off = 32; off; off >>= 1) p += __shfl_xor(p, off);
        if (lane == 0) gate[node] = p + gB;
    }
}

// -------- K8: GlobalAttention pool + final FC (block per graph)
__device__ __forceinline__ int lbound(const int* a, int n, int key) {
    int lo = 0, hi = n;
    while (lo < hi) { int mid = (lo + hi) >> 1; if (a[mid] < key) lo = mid + 1; else hi = mid; }
    return lo;
}

__global__ __launch_bounds__(256)
void k_pool(const int* __restrict__ batch, const float* __restrict__ gate,
            const float* __restrict__ h2, const float* __restrict__ hT,
            const float* __restrict__ fcW, const float* __restrict__ fcB,
            float* __restrict__ out, int n) {
    int b = blockIdx.x, tid = threadIdx.x;
    __shared__ float red[256];
    __shared__ float sc_sh[256];
    int start = lbound(batch, n, b);
    int end   = lbound(batch, n, b + 1);
    float m = -FLT_MAX;
    for (int i = start + tid; i < end; i += 256) m = fmaxf(m, gate[i]);
    red[tid] = m; __syncthreads();
    for (int s2 = 128; s2 > 0; s2 >>= 1) {
        if (tid < s2) red[tid] = fmaxf(red[tid], red[tid + s2]);
        __syncthreads();
    }
    m = red[0]; __syncthreads();
    float s = 0.f;
    for (int i = start + tid; i < end; i += 256) s += expf(gate[i] - m);
    red[tid] = s; __syncthreads();
    for (int s2 = 128; s2 > 0; s2 >>= 1) {
        if (tid < s2) red[tid] += red[tid + s2];
        __syncthreads();
    }
    float inv = 1.f / (red[0] + 1e-16f);
    __syncthreads();
    int j = tid & 127, half = tid >> 7;
    float acc = 0.f;
    for (int base = start; base < end; base += 256) {
        int cnt = min(256, end - base);
        __syncthreads();
        if (tid < cnt) sc_sh[tid] = expf(gate[base + tid] - m) * inv;
        __syncthreads();
        for (int ii = half; ii < cnt; ii += 2)
            acc += sc_sh[ii] * h2[(size_t)(base + ii) * 128 + j];
    }
    red[tid] = acc; __syncthreads();
    if (half == 0) sc_sh[j] = red[j] + red[128 + j];   // graph_rep[b][j]
    __syncthreads();
    float p = 0.f;
    if (tid < 128)
        p = fcW[tid] * sc_sh[tid] + fcW[128 + tid] * hT[(size_t)b * 128 + tid];
    red[tid] = p; __syncthreads();
    for (int s2 = 128; s2 > 0; s2 >>= 1) {
        if (tid < s2) red[tid] += red[tid + s2];
        __syncthreads();
    }
    if (tid == 0) out[b] = red[0] + fcB[0];
}

// ---- K9: MFMA LSTM, bf16 h/x in LDS; x-gate MFMAs in the barrier shadow.
// __launch_bounds__(512, 2): 8-wave block needs exactly 2 waves/SIMD -> VGPR
// cap 256, so the 80-VGPR weight fragment set stays register-resident
// (default heuristic capped at 104 -> per-step scratch spill, the prior
// ~100us floor in BOTH lstm variants).
__global__ __launch_bounds__(512, 2)
void k_lstm_mfma(const float* __restrict__ quant, const float* __restrict__ Wih,
                 const float* __restrict__ Whh, const float* __restrict__ bih,
                 const float* __restrict__ bhh, float* __restrict__ hstate) {
    __shared__ unsigned short h16[2][16][136];   // bf16, row stride 272B
    __shared__ unsigned short x16[16][1608];     // bf16, row stride 3216B
    int t = threadIdx.x, lane = t & 63, w = t >> 6;
    int b0   = blockIdx.x * 16;
    int l15  = lane & 15;
    int kq8  = (lane >> 4) * 8;
    int j    = w * 16 + l15;
    int rowq = (lane >> 4) * 4;
    float bi_i = bih[j]       + bhh[j];
    float bi_f = bih[128 + j] + bhh[128 + j];
    float bi_g = bih[256 + j] + bhh[256 + j];
    float bi_o = bih[384 + j] + bhh[384 + j];
    bf16x8 whh_f[4][4], wih_f[4];
    #pragma unroll
    for (int c = 0; c < 4; c++) {
        int col = c * 128 + j;
        #pragma unroll
        for (int kk = 0; kk < 4; kk++) {
            const float* wr = &Whh[(size_t)col * 128 + kk * 32 + kq8];
            whh_f[c][kk] = pack8(*reinterpret_cast<const float4*>(wr),
                                 *reinterpret_cast<const float4*>(wr + 4));
        }
        const float* wr = &Wih[(size_t)col * 32 + kq8];
        wih_f[c] = pack8(*reinterpret_cast<const float4*>(wr),
                         *reinterpret_cast<const float4*>(wr + 4));
    }
    unsigned* xw32 = reinterpret_cast<unsigned*>(&x16[0][0]);
    for (int p = t; p < 16 * 800; p += 512) {
        int r = p / 800, rem = p - r * 800;
        float2 f = *reinterpret_cast<const float2*>(
            &quant[(size_t)(b0 + r) * (KT * KQD) + rem * 2]);
        xw32[r * 804 + rem] = bfpack(f.x, f.y);
    }
    for (int p = t; p < 16 * 136; p += 512) {
        int r = p / 136, cc = p - r * 136;
        h16[0][r][cc] = 0;
    }
    float cst[4] = {0.f, 0.f, 0.f, 0.f};
    int cur = 0;
    __syncthreads();
    // prologue: x-gate contribution for step 0
    f32x4 xg[4];
    {
        bf16x8 ax = *reinterpret_cast<const bf16x8*>(&x16[l15][kq8]);
        #pragma unroll
        for (int c = 0; c < 4; c++) {
            f32x4 z = {0.f, 0.f, 0.f, 0.f};
            xg[c] = __builtin_amdgcn_mfma_f32_16x16x32_bf16(ax, wih_f[c], z, 0, 0, 0);
        }
    }
    for (int s = 0; s < KT; s++) {
        bf16x8 ah0 = *reinterpret_cast<const bf16x8*>(&h16[cur][l15][kq8]);
        bf16x8 ah1 = *reinterpret_cast<const bf16x8*>(&h16[cur][l15][32 + kq8]);
        bf16x8 ah2 = *reinterpret_cast<const bf16x8*>(&h16[cur][l15][64 + kq8]);
        bf16x8 ah3 = *reinterpret_cast<const bf16x8*>(&h16[cur][l15][96 + kq8]);
        f32x4 gs[4];
        #pragma unroll
        for (int c = 0; c < 4; c++) {
            f32x4 z = {0.f, 0.f, 0.f, 0.f};
            f32x4 a = __builtin_amdgcn_mfma_f32_16x16x32_bf16(ah0, whh_f[c][0], xg[c], 0, 0, 0);
            a = __builtin_amdgcn_mfma_f32_16x16x32_bf16(ah1, whh_f[c][1], a, 0, 0, 0);
            f32x4 b = __builtin_amdgcn_mfma_f32_16x16x32_bf16(ah2, whh_f[c][2], z, 0, 0, 0);
            b = __builtin_amdgcn_mfma_f32_16x16x32_bf16(ah3, whh_f[c][3], b, 0, 0, 0);
            gs[c] = a + b;    // frees a,b before next gate
        }
        int nxt = cur ^ 1;
        #pragma unroll
        for (int r = 0; r < 4; r++) {
            float ig = fsigm(gs[0][r] + bi_i);
            float fg = fsigm(gs[1][r] + bi_f);
            float gg = ftanh(gs[2][r] + bi_g);
            float og = fsigm(gs[3][r] + bi_o);
            cst[r] = fg * cst[r] + ig * gg;
            h16[nxt][rowq + r][j] = bf1(og * ftanh(cst[r]));
        }
        // x-gate MFMAs for step s+1 in the barrier shadow (independent of h)
        if (s + 1 < KT) {
            bf16x8 ax = *reinterpret_cast<const bf16x8*>(&x16[l15][(s + 1) * 32 + kq8]);
            #pragma unroll
            for (int c = 0; c < 4; c++) {
                f32x4 z = {0.f, 0.f, 0.f, 0.f};
                xg[c] = __builtin_amdgcn_mfma_f32_16x16x32_bf16(ax, wih_f[c], z, 0, 0, 0);
            }
        }
        __syncthreads();
        cur = nxt;
    }
    for (int p = t; p < 16 * KLH; p += 512) {
        int row = p >> 7, jj = p & 127;
        hstate[(size_t)(b0 + row) * KLH + jj] =
            __uint_as_float((unsigned)h16[cur][row][jj] << 16);
    }
}

// ----------------------------------------------------------------- launcher
extern "C" void kernel_launch(void* const* d_in, const int* in_sizes, int n_in,
                              void* d_out, int out_size, void* d_ws, size_t ws_size,
                              hipStream_t stream) {
    const float* x     = (const float*)d_in[0];
    const int*   ei    = (const int*)  d_in[1];
    const int*   batch = (const int*)  d_in[2];
    const float* quant = (const float*)d_in[3];
    const float* gatW  = (const float*)d_in[4];
    const float* attS  = (const float*)d_in[5];
    const float* attD  = (const float*)d_in[6];
    const float* gatB  = (const float*)d_in[7];
    const float* bn1g  = (const float*)d_in[8];
    const float* bn1b  = (const float*)d_in[9];
    const float* bn1m  = (const float*)d_in[10];
    const float* bn1v  = (const float*)d_in[11];
    const float* gcnW  = (const float*)d_in[12];
    const float* gcnB  = (const float*)d_in[13];
    const float* bn2g  = (const float*)d_in[14];
    const float* bn2b  = (const float*)d_in[15];
    const float* bn2m  = (const float*)d_in[16];
    const float* bn2v  = (const float*)d_in[17];
    const float* gateW = (const float*)d_in[18];
    const float* gateB = (const float*)d_in[19];
    const float* Wih   = (const float*)d_in[20];
    const float* Whh   = (const float*)d_in[21];
    const float* bih   = (const float*)d_in[22];
    const float* bhh   = (const float*)d_in[23];
    const float* fcW   = (const float*)d_in[24];
    const float* fcB   = (const float*)d_in[25];

    int N = in_sizes[0] / KIN;
    int E = in_sizes[1] / 2;
    int B = in_sizes[3] / (KT * KQD);

    char* ws = (char*)d_ws;
    size_t off = 0;
    auto alloc = [&](size_t bytes) -> void* {
        void* p = ws + off;
        off += (bytes + 511) & ~(size_t)511;
        return p;
    };
    int nb = (N + 4095) / 4096;
    int*      deg     = (int*)     alloc((size_t)N * 4);
    int*      offsets = (int*)     alloc((size_t)(N + 1) * 4);
    int*      cursor  = (int*)     alloc((size_t)N * 4);
    float*    dinv    = (float*)   alloc((size_t)N * 4);
    int*      csr_src = (int*)     alloc((size_t)E * 4);
    int*      bsum    = (int*)     alloc((size_t)nb * 4);
    float*    a_src   = (float*)   alloc((size_t)N * 16);
    float*    a_dst   = (float*)   alloc((size_t)N * 16);
    unsigned* xwb     = (unsigned*)alloc((size_t)N * 256);  // bf16 gemm out; reused as hwb
    float*    hbuf    = (float*)   alloc((size_t)N * 512);  // f32 gat out; reused as h2
    float*    gate    = (float*)   alloc((size_t)N * 4);
    float*    hstate  = (float*)   alloc((size_t)B * KLH * 4);

    hipMemsetAsync(deg, 0, (size_t)N * 4, stream);
    int eb = (E + 255) / 256;
    k_deg   <<<eb, 256, 0, stream>>>(ei, E, deg);
    k_scan_a<<<nb, 1024, 0, stream>>>(deg, N, bsum);
    k_scan_b<<<1, 64, 0, stream>>>(bsum, nb);
    k_scan_c<<<nb, 1024, 0, stream>>>(deg, N, bsum, offsets, cursor, dinv);
    k_fill  <<<eb, 256, 0, stream>>>(ei, E, cursor, csr_src);

    k_lstm_mfma<<<B / 16, 512, 0, stream>>>(quant, Wih, Whh, bih, bhh, hstate);

    k_gemm_mfma<true ><<<512, 256, 0, stream>>>(x, gatW, xwb, N, attS, attD, a_src, a_dst);
    k_gat_agg<<<3072, 256, 0, stream>>>(offsets, csr_src, a_src, a_dst, xwb, gatB,
                                        bn1g, bn1b, bn1m, bn1v, hbuf, N);
    k_gemm_mfma<false><<<512, 256, 0, stream>>>(hbuf, gcnW, xwb, N,
                                                nullptr, nullptr, nullptr, nullptr);
    k_gcn_agg<<<3072, 256, 0, stream>>>(offsets, csr_src, dinv, xwb, gcnB,
                                        bn2g, bn2b, bn2m, bn2v, gateW, gateB,
                                        hbuf, gate, N);
    k_pool<<<B, 256, 0, stream>>>(batch, gate, hbuf, hstate, fcW, fcB,
                                  (float*)d_out, N);
}

// Round 10
// 432.129 us; speedup vs baseline: 1.0239x; 1.0239x over previous
//
#include <hip/hip_runtime.h>
#include <cfloat>
#include <cstddef>

constexpr int KIN   = 128;
constexpr int KQD   = 32;
constexpr int KT    = 50;
constexpr int KLH   = 128;
constexpr float BN_EPS = 1e-5f;

typedef __attribute__((ext_vector_type(8))) short bf16x8;
typedef __attribute__((ext_vector_type(4))) float f32x4;
union U8 { bf16x8 v; unsigned u[4]; };

__device__ __forceinline__ float elu_f(float x)  { return x > 0.f ? x : expm1f(x); }
__device__ __forceinline__ float leaky_f(float x){ return x > 0.f ? x : 0.2f * x; }
__device__ __forceinline__ float fsigm(float x)  { return 1.f / (1.f + __expf(-x)); }
__device__ __forceinline__ float ftanh(float x)  { return 1.f - 2.f / (__expf(2.f * x) + 1.f); }

__device__ __forceinline__ unsigned bfpack(float lo, float hi) {
    unsigned ul = __float_as_uint(lo), uh = __float_as_uint(hi);
    ul += 0x7FFFu + ((ul >> 16) & 1u);
    uh += 0x7FFFu + ((uh >> 16) & 1u);
    return (ul >> 16) | (uh & 0xFFFF0000u);
}
__device__ __forceinline__ unsigned short bf1(float v) {
    unsigned u = __float_as_uint(v);
    u += 0x7FFFu + ((u >> 16) & 1u);
    return (unsigned short)(u >> 16);
}
__device__ __forceinline__ float bflo(unsigned u) { return __uint_as_float(u << 16); }
__device__ __forceinline__ float bfhi(unsigned u) { return __uint_as_float(u & 0xFFFF0000u); }

__device__ __forceinline__ bf16x8 pack8(float4 p, float4 q) {
    U8 t;
    t.u[0] = bfpack(p.x, p.y); t.u[1] = bfpack(p.z, p.w);
    t.u[2] = bfpack(q.x, q.y); t.u[3] = bfpack(q.z, q.w);
    return t.v;
}

// ---------------------------------------------------------------- K1: degree
__global__ void k_deg(const int* __restrict__ ei, int E, int* __restrict__ deg) {
    int e = blockIdx.x * blockDim.x + threadIdx.x;
    if (e < E) atomicAdd(&deg[ei[E + e]], 1);
}

// ---------------- K2a/b/c: hierarchical exclusive scan (parallel)
__global__ __launch_bounds__(1024)
void k_scan_a(const int* __restrict__ deg, int n, int* __restrict__ bsum) {
    __shared__ int wsum[16];
    int tid = threadIdx.x, lane = tid & 63, w = tid >> 6;
    int i0 = blockIdx.x * 4096 + tid * 4;
    int t = 0;
    #pragma unroll
    for (int j = 0; j < 4; j++) t += (i0 + j < n) ? deg[i0 + j] : 0;
    #pragma unroll
    for (int d = 1; d < 64; d <<= 1) t += __shfl_xor(t, d);
    if (lane == 0) wsum[w] = t;
    __syncthreads();
    if (tid == 0) {
        int s = 0;
        #pragma unroll
        for (int k = 0; k < 16; k++) s += wsum[k];
        bsum[blockIdx.x] = s;
    }
}

__global__ void k_scan_b(int* __restrict__ bsum, int nb) {
    if (threadIdx.x == 0) {
        int run = 0;
        for (int i = 0; i < nb; i++) { int v = bsum[i]; bsum[i] = run; run += v; }
    }
}

__global__ __launch_bounds__(1024)
void k_scan_c(const int* __restrict__ deg, int n, const int* __restrict__ bsum,
              int* __restrict__ offsets, int* __restrict__ cursor,
              float* __restrict__ dinv) {
    __shared__ int wsum[16];
    int tid = threadIdx.x, lane = tid & 63, w = tid >> 6;
    int i0 = blockIdx.x * 4096 + tid * 4;
    int v[4];
    #pragma unroll
    for (int j = 0; j < 4; j++) v[j] = (i0 + j < n) ? deg[i0 + j] : 0;
    int tsum = v[0] + v[1] + v[2] + v[3];
    int sc = tsum;
    #pragma unroll
    for (int d = 1; d < 64; d <<= 1) {
        int o = __shfl_up(sc, d);
        if (lane >= d) sc += o;
    }
    if (lane == 63) wsum[w] = sc;
    __syncthreads();
    if (w == 0) {
        int xx = (lane < 16) ? wsum[lane] : 0;
        #pragma unroll
        for (int d = 1; d < 16; d <<= 1) {
            int o = __shfl_up(xx, d);
            if (lane >= d) xx += o;
        }
        if (lane < 16) wsum[lane] = xx;
    }
    __syncthreads();
    int run = bsum[blockIdx.x] + ((w > 0) ? wsum[w - 1] : 0) + sc - tsum;
    #pragma unroll
    for (int j = 0; j < 4; j++) {
        int i = i0 + j;
        if (i < n) {
            cursor[i]      = run;
            offsets[i + 1] = run + v[j];
            dinv[i]        = rsqrtf((float)(v[j] + 1));
            run += v[j];
        }
    }
    if (blockIdx.x == 0 && tid == 0) offsets[0] = 0;
}

// ---------------------------------------------------------------- K3: fill
__global__ void k_fill(const int* __restrict__ ei, int E, int* __restrict__ cursor,
                       int* __restrict__ csr_src) {
    int e = blockIdx.x * blockDim.x + threadIdx.x;
    if (e < E) {
        int s = ei[e], d = ei[E + e];
        int pos = atomicAdd(&cursor[d], 1);
        csr_src[pos] = s;
    }
}

// ------------- K4/K6: MFMA bf16 GEMM  Y[r,:] = X[r,:] @ W,  128x128 weights
template <bool ATT>
__global__ __launch_bounds__(256, 4)
void k_gemm_mfma(const float* __restrict__ X, const float* __restrict__ W,
                 unsigned* __restrict__ Yb, int nrows,
                 const float* __restrict__ attS, const float* __restrict__ attD,
                 float* __restrict__ a_src, float* __restrict__ a_dst) {
    __shared__ float tile[16][132];
    __shared__ float as_sh[128], ad_sh[128];
    int tid  = threadIdx.x;
    int lane = tid & 63;
    int wv   = tid >> 6;
    if (ATT && tid < 128) { as_sh[tid] = attS[tid]; ad_sh[tid] = attD[tid]; }
    int l16 = lane & 15;
    int kq  = (lane >> 4) * 8;
    bf16x8 bfr[2][4];
    #pragma unroll
    for (int nt = 0; nt < 2; nt++) {
        int n = wv * 32 + nt * 16 + l16;
        #pragma unroll
        for (int kk = 0; kk < 4; kk++) {
            int k0 = kk * 32 + kq;
            float f[8];
            #pragma unroll
            for (int j = 0; j < 8; j++) f[j] = W[(size_t)(k0 + j) * 128 + n];
            U8 t;
            t.u[0] = bfpack(f[0], f[1]); t.u[1] = bfpack(f[2], f[3]);
            t.u[2] = bfpack(f[4], f[5]); t.u[3] = bfpack(f[6], f[7]);
            bfr[nt][kk] = t.v;
        }
    }
    int nch = (nrows + 15) / 16;
    for (int ch = blockIdx.x; ch < nch; ch += gridDim.x) {
        int r0 = ch * 16;
        int r  = r0 + l16;
        bool rok = r < nrows;
        const float* xr = X + (size_t)r * 128 + kq;
        float4 z4 = make_float4(0.f, 0.f, 0.f, 0.f);
        bf16x8 afr[4];
        #pragma unroll
        for (int kk = 0; kk < 4; kk++) {
            float4 p = rok ? *reinterpret_cast<const float4*>(xr + kk * 32)     : z4;
            float4 q = rok ? *reinterpret_cast<const float4*>(xr + kk * 32 + 4) : z4;
            afr[kk] = pack8(p, q);
        }
        f32x4 acc0 = {0.f, 0.f, 0.f, 0.f};
        f32x4 acc1 = {0.f, 0.f, 0.f, 0.f};
        #pragma unroll
        for (int kk = 0; kk < 4; kk++) {
            acc0 = __builtin_amdgcn_mfma_f32_16x16x32_bf16(afr[kk], bfr[0][kk], acc0, 0, 0, 0);
            acc1 = __builtin_amdgcn_mfma_f32_16x16x32_bf16(afr[kk], bfr[1][kk], acc1, 0, 0, 0);
        }
        __syncthreads();
        int rowb = (lane >> 4) * 4;
        int cb   = wv * 32 + l16;
        #pragma unroll
        for (int reg = 0; reg < 4; reg++) {
            tile[rowb + reg][cb]      = acc0[reg];
            tile[rowb + reg][cb + 16] = acc1[reg];
        }
        __syncthreads();
        #pragma unroll
        for (int i = 0; i < 4; i++) {
            int idx = tid + i * 256;
            int row = idx >> 6, cp = idx & 63;
            int rr = r0 + row;
            if (rr < nrows) {
                float2 f = *reinterpret_cast<const float2*>(&tile[row][cp * 2]);
                Yb[(size_t)rr * 64 + cp] = bfpack(f.x, f.y);
            }
        }
        if (ATT && tid < 64) {
            int rr2 = tid >> 2, h = tid & 3;
            if (r0 + rr2 < nrows) {
                float ps = 0.f, pd = 0.f;
                #pragma unroll
                for (int j = 0; j < 32; j++) {
                    float v = tile[rr2][h * 32 + j];
                    ps += v * as_sh[h * 32 + j];
                    pd += v * ad_sh[h * 32 + j];
                }
                a_src[(size_t)(r0 + rr2) * 4 + h] = ps;
                a_dst[(size_t)(r0 + rr2) * 4 + h] = pd;
            }
        }
    }
}

// ---------- K5: GAT aggregate — wave/node, alpha in LDS, bf16-pair gather
__global__ __launch_bounds__(256)
void k_gat_agg(const int* __restrict__ offsets, const int* __restrict__ csr_src,
               const float* __restrict__ a_src, const float* __restrict__ a_dst,
               const unsigned* __restrict__ xwb, const float* __restrict__ bias,
               const float* __restrict__ g1, const float* __restrict__ b1,
               const float* __restrict__ mu1, const float* __restrict__ var1,
               float* __restrict__ hout, int n) {
    __shared__ int   src_sh[4][64];
    __shared__ float al_sh[4][4][64];
    int lane = threadIdx.x & 63;
    int wv   = threadIdx.x >> 6;
    int wid  = (blockIdx.x * blockDim.x + threadIdx.x) >> 6;
    int nw   = (gridDim.x * blockDim.x) >> 6;
    int hP   = lane >> 4;
    int c0 = lane * 2, c1 = c0 + 1;
    float bi0 = bias[c0], bi1 = bias[c1];
    float A0 = g1[c0] * rsqrtf(var1[c0] + BN_EPS);
    float A1 = g1[c1] * rsqrtf(var1[c1] + BN_EPS);
    float B0 = b1[c0] - mu1[c0] * A0;
    float B1 = b1[c1] - mu1[c1] * A1;
    for (int node = wid; node < n; node += nw) {
        int beg = offsets[node], end = offsets[node + 1];
        int rowlen = end - beg, total = rowlen + 1;
        float4 adv = *reinterpret_cast<const float4*>(&a_dst[(size_t)node * 4]);
        int sv = (lane < rowlen) ? csr_src[beg + lane] : node;
        float4 as4 = *reinterpret_cast<const float4*>(&a_src[(size_t)sv * 4]);
        float e0 = leaky_f(as4.x + adv.x), e1 = leaky_f(as4.y + adv.y);
        float e2 = leaky_f(as4.z + adv.z), e3 = leaky_f(as4.w + adv.w);
        float m[4] = {-FLT_MAX, -FLT_MAX, -FLT_MAX, -FLT_MAX};
        if (lane < total) { m[0] = e0; m[1] = e1; m[2] = e2; m[3] = e3; }
        for (int i = lane + 64; i < total; i += 64) {
            int src = (i < rowlen) ? csr_src[beg + i] : node;
            float4 a4 = *reinterpret_cast<const float4*>(&a_src[(size_t)src * 4]);
            m[0] = fmaxf(m[0], leaky_f(a4.x + adv.x));
            m[1] = fmaxf(m[1], leaky_f(a4.y + adv.y));
            m[2] = fmaxf(m[2], leaky_f(a4.z + adv.z));
            m[3] = fmaxf(m[3], leaky_f(a4.w + adv.w));
        }
        #pragma unroll
        for (int off = 32; off; off >>= 1) {
            #pragma unroll
            for (int h = 0; h < 4; h++) m[h] = fmaxf(m[h], __shfl_xor(m[h], off));
        }
        float ex[4] = {0.f, 0.f, 0.f, 0.f};
        if (lane < total) {
            ex[0] = expf(e0 - m[0]); ex[1] = expf(e1 - m[1]);
            ex[2] = expf(e2 - m[2]); ex[3] = expf(e3 - m[3]);
        }
        float s[4] = {ex[0], ex[1], ex[2], ex[3]};
        for (int i = lane + 64; i < total; i += 64) {
            int src = (i < rowlen) ? csr_src[beg + i] : node;
            float4 a4 = *reinterpret_cast<const float4*>(&a_src[(size_t)src * 4]);
            s[0] += expf(leaky_f(a4.x + adv.x) - m[0]);
            s[1] += expf(leaky_f(a4.y + adv.y) - m[1]);
            s[2] += expf(leaky_f(a4.z + adv.z) - m[2]);
            s[3] += expf(leaky_f(a4.w + adv.w) - m[3]);
        }
        #pragma unroll
        for (int off = 32; off; off >>= 1) {
            #pragma unroll
            for (int h = 0; h < 4; h++) s[h] += __shfl_xor(s[h], off);
        }
        float inv[4];
        #pragma unroll
        for (int h = 0; h < 4; h++) inv[h] = 1.f / (s[h] + 1e-16f);
        src_sh[wv][lane] = sv;
        #pragma unroll
        for (int h = 0; h < 4; h++) al_sh[wv][h][lane] = ex[h] * inv[h];
        __builtin_amdgcn_wave_barrier();
        float acc0 = 0.f, acc1 = 0.f;
        int cnt = min(total, 64);
        {
            int i = 0;
            for (; i + 4 <= cnt; i += 4) {
                int s0 = src_sh[wv][i],     s1 = src_sh[wv][i + 1];
                int s2 = src_sh[wv][i + 2], s3 = src_sh[wv][i + 3];
                float a0 = al_sh[wv][hP][i],     a1 = al_sh[wv][hP][i + 1];
                float a2 = al_sh[wv][hP][i + 2], a3 = al_sh[wv][hP][i + 3];
                unsigned u0 = xwb[(size_t)s0 * 64 + lane];
                unsigned u1 = xwb[(size_t)s1 * 64 + lane];
                unsigned u2 = xwb[(size_t)s2 * 64 + lane];
                unsigned u3 = xwb[(size_t)s3 * 64 + lane];
                acc0 += a0 * bflo(u0); acc1 += a0 * bfhi(u0);
                acc0 += a1 * bflo(u1); acc1 += a1 * bfhi(u1);
                acc0 += a2 * bflo(u2); acc1 += a2 * bfhi(u2);
                acc0 += a3 * bflo(u3); acc1 += a3 * bfhi(u3);
            }
            for (; i < cnt; i++) {
                int src  = src_sh[wv][i];
                float aP = al_sh[wv][hP][i];
                unsigned u = xwb[(size_t)src * 64 + lane];
                acc0 += aP * bflo(u);
                acc1 += aP * bfhi(u);
            }
        }
        for (int base = 64; base < total; base += 64) {
            __builtin_amdgcn_wave_barrier();
            int i = base + lane;
            int src2 = node;
            float a0v = 0.f, a1v = 0.f, a2v = 0.f, a3v = 0.f;
            if (i < total) {
                if (i < rowlen) src2 = csr_src[beg + i];
                float4 a4 = *reinterpret_cast<const float4*>(&a_src[(size_t)src2 * 4]);
                a0v = expf(leaky_f(a4.x + adv.x) - m[0]) * inv[0];
                a1v = expf(leaky_f(a4.y + adv.y) - m[1]) * inv[1];
                a2v = expf(leaky_f(a4.z + adv.z) - m[2]) * inv[2];
                a3v = expf(leaky_f(a4.w + adv.w) - m[3]) * inv[3];
            }
            src_sh[wv][lane] = src2;
            al_sh[wv][0][lane] = a0v; al_sh[wv][1][lane] = a1v;
            al_sh[wv][2][lane] = a2v; al_sh[wv][3][lane] = a3v;
            __builtin_amdgcn_wave_barrier();
            int cnt2 = min(total - base, 64);
            for (int j = 0; j < cnt2; j++) {
                int src  = src_sh[wv][j];
                float aP = al_sh[wv][hP][j];
                unsigned u = xwb[(size_t)src * 64 + lane];
                acc0 += aP * bflo(u);
                acc1 += aP * bfhi(u);
            }
        }
        __builtin_amdgcn_wave_barrier();
        float vA = elu_f(acc0 + bi0);
        float vB = elu_f(acc1 + bi1);
        vA = vA * A0 + B0;
        vB = vB * A1 + B1;
        *reinterpret_cast<float2*>(&hout[(size_t)node * 128 + c0]) =
            make_float2(vA, vB);
    }
}

// ---------- K7: GCN aggregate — wave/node, bf16-pair gather + gate dot
__global__ __launch_bounds__(256)
void k_gcn_agg(const int* __restrict__ offsets, const int* __restrict__ csr_src,
               const float* __restrict__ dinv, const unsigned* __restrict__ hwb,
               const float* __restrict__ bias,
               const float* __restrict__ g2, const float* __restrict__ b2,
               const float* __restrict__ mu2, const float* __restrict__ var2,
               const float* __restrict__ gateW, const float* __restrict__ gateB,
               float* __restrict__ h2, float* __restrict__ gate, int n) {
    __shared__ int   src_sh[4][64];
    __shared__ float w_sh[4][64];
    int lane = threadIdx.x & 63;
    int wv   = threadIdx.x >> 6;
    int wid  = (blockIdx.x * blockDim.x + threadIdx.x) >> 6;
    int nw   = (gridDim.x * blockDim.x) >> 6;
    int c0 = lane * 2, c1 = c0 + 1;
    float bi0 = bias[c0], bi1 = bias[c1];
    float A0 = g2[c0] * rsqrtf(var2[c0] + BN_EPS);
    float A1 = g2[c1] * rsqrtf(var2[c1] + BN_EPS);
    float B0 = b2[c0] - mu2[c0] * A0;
    float B1 = b2[c1] - mu2[c1] * A1;
    float gw0 = gateW[c0], gw1 = gateW[c1], gB = gateB[0];
    for (int node = wid; node < n; node += nw) {
        int beg = offsets[node], end = offsets[node + 1];
        int rowlen = end - beg;
        float dn = dinv[node];
        unsigned us = hwb[(size_t)node * 64 + lane];
        float acc0 = dn * dn * bflo(us);
        float acc1 = dn * dn * bfhi(us);
        for (int base = 0; base < rowlen; base += 64) {
            __builtin_amdgcn_wave_barrier();
            int i = base + lane;
            int src2 = node;
            float wv2 = 0.f;
            if (i < rowlen) { src2 = csr_src[beg + i]; wv2 = dinv[src2] * dn; }
            src_sh[wv][lane] = src2;
            w_sh[wv][lane]   = wv2;
            __builtin_amdgcn_wave_barrier();
            int cnt = min(rowlen - base, 64);
            int j = 0;
            for (; j + 4 <= cnt; j += 4) {
                int s0 = src_sh[wv][j],     s1 = src_sh[wv][j + 1];
                int s2 = src_sh[wv][j + 2], s3 = src_sh[wv][j + 3];
                float w0 = w_sh[wv][j],     w1 = w_sh[wv][j + 1];
                float w2 = w_sh[wv][j + 2], w3 = w_sh[wv][j + 3];
                unsigned u0 = hwb[(size_t)s0 * 64 + lane];
                unsigned u1 = hwb[(size_t)s1 * 64 + lane];
                unsigned u2 = hwb[(size_t)s2 * 64 + lane];
                unsigned u3 = hwb[(size_t)s3 * 64 + lane];
                acc0 += w0 * bflo(u0); acc1 += w0 * bfhi(u0);
                acc0 += w1 * bflo(u1); acc1 += w1 * bfhi(u1);
                acc0 += w2 * bflo(u2); acc1 += w2 * bfhi(u2);
                acc0 += w3 * bflo(u3); acc1 += w3 * bfhi(u3);
            }
            for (; j < cnt; j++) {
                int src = src_sh[wv][j];
                float w = w_sh[wv][j];
                unsigned u = hwb[(size_t)src * 64 + lane];
                acc0 += w * bflo(u);
                acc1 += w * bfhi(u);
            }
        }
        __builtin_amdgcn_wave_barrier();
        float vA = elu_f(acc0 + bi0);
        float vB = elu_f(acc1 + bi1);
        vA = vA * A0 + B0;
        vB = vB * A1 + B1;
        *reinterpret_cast<float2*>(&h2[(size_t)node * 128 + c0]) =
            make_float2(vA, vB);
        float p = vA * gw0 + vB * gw1;
        #pragma unroll
        for (int off = 32; off; off >>= 1) p += __shfl_xor(p, off);
        if (lane == 0) gate[node] = p + gB;
    }
}

// -------- K8: GlobalAttention pool + final FC (block per graph)
__device__ __forceinline__ int lbound(const int* a, int n, int key) {
    int lo = 0, hi = n;
    while (lo < hi) { int mid = (lo + hi) >> 1; if (a[mid] < key) lo = mid + 1; else hi = mid; }
    return lo;
}

__global__ __launch_bounds__(256)
void k_pool(const int* __restrict__ batch, const float* __restrict__ gate,
            const float* __restrict__ h2, const float* __restrict__ hT,
            const float* __restrict__ fcW, const float* __restrict__ fcB,
            float* __restrict__ out, int n) {
    int b = blockIdx.x, tid = threadIdx.x;
    __shared__ float red[256];
    __shared__ float sc_sh[256];
    int start = lbound(batch, n, b);
    int end   = lbound(batch, n, b + 1);
    float m = -FLT_MAX;
    for (int i = start + tid; i < end; i += 256) m = fmaxf(m, gate[i]);
    red[tid] = m; __syncthreads();
    for (int s2 = 128; s2 > 0; s2 >>= 1) {
        if (tid < s2) red[tid] = fmaxf(red[tid], red[tid + s2]);
        __syncthreads();
    }
    m = red[0]; __syncthreads();
    float s = 0.f;
    for (int i = start + tid; i < end; i += 256) s += expf(gate[i] - m);
    red[tid] = s; __syncthreads();
    for (int s2 = 128; s2 > 0; s2 >>= 1) {
        if (tid < s2) red[tid] += red[tid + s2];
        __syncthreads();
    }
    float inv = 1.f / (red[0] + 1e-16f);
    __syncthreads();
    int j = tid & 127, half = tid >> 7;
    float acc = 0.f;
    for (int base = start; base < end; base += 256) {
        int cnt = min(256, end - base);
        __syncthreads();
        if (tid < cnt) sc_sh[tid] = expf(gate[base + tid] - m) * inv;
        __syncthreads();
        for (int ii = half; ii < cnt; ii += 2)
            acc += sc_sh[ii] * h2[(size_t)(base + ii) * 128 + j];
    }
    red[tid] = acc; __syncthreads();
    if (half == 0) sc_sh[j] = red[j] + red[128 + j];   // graph_rep[b][j]
    __syncthreads();
    float p = 0.f;
    if (tid < 128)
        p = fcW[tid] * sc_sh[tid] + fcW[128 + tid] * hT[(size_t)b * 128 + tid];
    red[tid] = p; __syncthreads();
    for (int s2 = 128; s2 > 0; s2 >>= 1) {
        if (tid < s2) red[tid] += red[tid + s2];
        __syncthreads();
    }
    if (tid == 0) out[b] = red[0] + fcB[0];
}

// ---- K9a: x-projection for all (batch,step): xproj = quant@WihT + bih + bhh,
//      stored pre-swizzled in MFMA accumulator layout:
//      xproj[((chunk*KT + s)*32 + tc)*256 + lane*4 + r]  (tc = gate*8 + wave)
__global__ __launch_bounds__(256)
void k_xproj(const float* __restrict__ quant, const float* __restrict__ Wih,
             const float* __restrict__ bih, const float* __restrict__ bhh,
             float* __restrict__ xproj) {
    int blk = blockIdx.x;
    int chunk = blk / KT, s = blk % KT;
    int lane = threadIdx.x & 63, w = threadIdx.x >> 6;
    int l15 = lane & 15, kq8 = (lane >> 4) * 8;
    int b = chunk * 16 + l15;
    const float* xr = &quant[(size_t)b * (KT * KQD) + s * KQD + kq8];
    bf16x8 ax = pack8(*reinterpret_cast<const float4*>(xr),
                      *reinterpret_cast<const float4*>(xr + 4));
    #pragma unroll
    for (int ti = 0; ti < 8; ti++) {
        int tc = w * 8 + ti;             // gate = w, sub-tile = ti
        int gcol = w * 128 + ti * 16 + l15;
        const float* wr = &Wih[(size_t)gcol * KQD + kq8];
        bf16x8 bw = pack8(*reinterpret_cast<const float4*>(wr),
                          *reinterpret_cast<const float4*>(wr + 4));
        f32x4 acc = {0.f, 0.f, 0.f, 0.f};
        acc = __builtin_amdgcn_mfma_f32_16x16x32_bf16(ax, bw, acc, 0, 0, 0);
        float bv = bih[gcol] + bhh[gcol];
        acc[0] += bv; acc[1] += bv; acc[2] += bv; acc[3] += bv;
        *reinterpret_cast<f32x4*>(
            &xproj[(((size_t)chunk * KT + s) * 32 + tc) * 256 + lane * 4]) = acc;
    }
}

// ---- K9b: MFMA LSTM, minimal register footprint: x-projection precomputed
//      (loaded per step as coalesced f32x4 C-init), one ah fragment live at a
//      time, conflict-free h layout (row stride 148 ushorts = 74 dwords:
//      write-quads hit bank octets {0,8,16,24}; reads 2-way-free).
__global__ __launch_bounds__(512)
void k_lstm2(const float* __restrict__ xproj, const float* __restrict__ Whh,
             float* __restrict__ hstate) {
    __shared__ unsigned short h16[2][16][148];
    int t = threadIdx.x, lane = t & 63, w = t >> 6;
    int chunk = blockIdx.x;
    int l15 = lane & 15, kq8 = (lane >> 4) * 8;
    int j = w * 16 + l15;
    int rowq = (lane >> 4) * 4;
    // Whh fragments: whh_f[gate][kk]; B[k][n] = Whh[gate*128 + j][k]
    bf16x8 whh_f[4][4];
    #pragma unroll
    for (int c = 0; c < 4; c++) {
        int col = c * 128 + j;
        #pragma unroll
        for (int kk = 0; kk < 4; kk++) {
            const float* wr = &Whh[(size_t)col * 128 + kk * 32 + kq8];
            whh_f[c][kk] = pack8(*reinterpret_cast<const float4*>(wr),
                                 *reinterpret_cast<const float4*>(wr + 4));
        }
    }
    for (int p = t; p < 16 * 148; p += 512) {
        int r = p / 148, cc = p - r * 148;
        h16[0][r][cc] = 0;
    }
    float cst[4] = {0.f, 0.f, 0.f, 0.f};
    const float* xb = xproj + ((size_t)chunk * KT) * 32 * 256;
    // prefetch step-0 gate inits
    f32x4 xgA = *reinterpret_cast<const f32x4*>(&xb[(0 * 8 + w) * 256 + lane * 4]);
    f32x4 xgB = *reinterpret_cast<const f32x4*>(&xb[(1 * 8 + w) * 256 + lane * 4]);
    f32x4 xgC = *reinterpret_cast<const f32x4*>(&xb[(2 * 8 + w) * 256 + lane * 4]);
    f32x4 xgD = *reinterpret_cast<const f32x4*>(&xb[(3 * 8 + w) * 256 + lane * 4]);
    int cur = 0;
    __syncthreads();
    for (int s = 0; s < KT; s++) {
        f32x4 ai = xgA, af = xgB, ag = xgC, ao = xgD;
        #pragma unroll
        for (int kk = 0; kk < 4; kk++) {
            bf16x8 ah = *reinterpret_cast<const bf16x8*>(&h16[cur][l15][kk * 32 + kq8]);
            ai = __builtin_amdgcn_mfma_f32_16x16x32_bf16(ah, whh_f[0][kk], ai, 0, 0, 0);
            af = __builtin_amdgcn_mfma_f32_16x16x32_bf16(ah, whh_f[1][kk], af, 0, 0, 0);
            ag = __builtin_amdgcn_mfma_f32_16x16x32_bf16(ah, whh_f[2][kk], ag, 0, 0, 0);
            ao = __builtin_amdgcn_mfma_f32_16x16x32_bf16(ah, whh_f[3][kk], ao, 0, 0, 0);
        }
        if (s + 1 < KT) {   // next-step gate inits, latency hidden under MFMA/VALU
            const float* xs = &xb[((size_t)(s + 1) * 32 + w) * 256 + lane * 4];
            xgA = *reinterpret_cast<const f32x4*>(&xs[0 * 8 * 256]);
            xgB = *reinterpret_cast<const f32x4*>(&xs[1 * 8 * 256]);
            xgC = *reinterpret_cast<const f32x4*>(&xs[2 * 8 * 256]);
            xgD = *reinterpret_cast<const f32x4*>(&xs[3 * 8 * 256]);
        }
        int nxt = cur ^ 1;
        #pragma unroll
        for (int r = 0; r < 4; r++) {
            float ig = fsigm(ai[r]);
            float fg = fsigm(af[r]);
            float gg = ftanh(ag[r]);
            float og = fsigm(ao[r]);
            cst[r] = fg * cst[r] + ig * gg;
            h16[nxt][rowq + r][j] = bf1(og * ftanh(cst[r]));
        }
        __syncthreads();
        cur = nxt;
    }
    int b0 = chunk * 16;
    for (int p = t; p < 16 * KLH; p += 512) {
        int row = p >> 7, jj = p & 127;
        hstate[(size_t)(b0 + row) * KLH + jj] =
            __uint_as_float((unsigned)h16[cur][row][jj] << 16);
    }
}

// ----------------------------------------------------------------- launcher
extern "C" void kernel_launch(void* const* d_in, const int* in_sizes, int n_in,
                              void* d_out, int out_size, void* d_ws, size_t ws_size,
                              hipStream_t stream) {
    const float* x     = (const float*)d_in[0];
    const int*   ei    = (const int*)  d_in[1];
    const int*   batch = (const int*)  d_in[2];
    const float* quant = (const float*)d_in[3];
    const float* gatW  = (const float*)d_in[4];
    const float* attS  = (const float*)d_in[5];
    const float* attD  = (const float*)d_in[6];
    const float* gatB  = (const float*)d_in[7];
    const float* bn1g  = (const float*)d_in[8];
    const float* bn1b  = (const float*)d_in[9];
    const float* bn1m  = (const float*)d_in[10];
    const float* bn1v  = (const float*)d_in[11];
    const float* gcnW  = (const float*)d_in[12];
    const float* gcnB  = (const float*)d_in[13];
    const float* bn2g  = (const float*)d_in[14];
    const float* bn2b  = (const float*)d_in[15];
    const float* bn2m  = (const float*)d_in[16];
    const float* bn2v  = (const float*)d_in[17];
    const float* gateW = (const float*)d_in[18];
    const float* gateB = (const float*)d_in[19];
    const float* Wih   = (const float*)d_in[20];
    const float* Whh   = (const float*)d_in[21];
    const float* bih   = (const float*)d_in[22];
    const float* bhh   = (const float*)d_in[23];
    const float* fcW   = (const float*)d_in[24];
    const float* fcB   = (const float*)d_in[25];

    int N = in_sizes[0] / KIN;
    int E = in_sizes[1] / 2;
    int B = in_sizes[3] / (KT * KQD);
    int nchunks = B / 16;

    char* ws = (char*)d_ws;
    size_t off = 0;
    auto alloc = [&](size_t bytes) -> void* {
        void* p = ws + off;
        off += (bytes + 511) & ~(size_t)511;
        return p;
    };
    int nb = (N + 4095) / 4096;
    int*      deg     = (int*)     alloc((size_t)N * 4);
    int*      offsets = (int*)     alloc((size_t)(N + 1) * 4);
    int*      cursor  = (int*)     alloc((size_t)N * 4);
    float*    dinv    = (float*)   alloc((size_t)N * 4);
    int*      csr_src = (int*)     alloc((size_t)E * 4);
    int*      bsum    = (int*)     alloc((size_t)nb * 4);
    float*    a_src   = (float*)   alloc((size_t)N * 16);
    float*    a_dst   = (float*)   alloc((size_t)N * 16);
    unsigned* xwb     = (unsigned*)alloc((size_t)N * 256);  // bf16 gemm out; reused as hwb
    float*    hbuf    = (float*)   alloc((size_t)N * 512);  // f32 gat out; reused as h2
    float*    gate    = (float*)   alloc((size_t)N * 4);
    float*    hstate  = (float*)   alloc((size_t)B * KLH * 4);
    float*    xproj   = (float*)   alloc((size_t)nchunks * KT * 32 * 256 * 4);

    hipMemsetAsync(deg, 0, (size_t)N * 4, stream);
    int eb = (E + 255) / 256;
    k_deg   <<<eb, 256, 0, stream>>>(ei, E, deg);
    k_scan_a<<<nb, 1024, 0, stream>>>(deg, N, bsum);
    k_scan_b<<<1, 64, 0, stream>>>(bsum, nb);
    k_scan_c<<<nb, 1024, 0, stream>>>(deg, N, bsum, offsets, cursor, dinv);
    k_fill  <<<eb, 256, 0, stream>>>(ei, E, cursor, csr_src);

    k_xproj<<<nchunks * KT, 256, 0, stream>>>(quant, Wih, bih, bhh, xproj);
    k_lstm2<<<nchunks, 512, 0, stream>>>(xproj, Whh, hstate);

    k_gemm_mfma<true ><<<512, 256, 0, stream>>>(x, gatW, xwb, N, attS, attD, a_src, a_dst);
    k_gat_agg<<<3072, 256, 0, stream>>>(offsets, csr_src, a_src, a_dst, xwb, gatB,
                                        bn1g, bn1b, bn1m, bn1v, hbuf, N);
    k_gemm_mfma<false><<<512, 256, 0, stream>>>(hbuf, gcnW, xwb, N,
                                                nullptr, nullptr, nullptr, nullptr);
    k_gcn_agg<<<3072, 256, 0, stream>>>(offsets, csr_src, dinv, xwb, gcnB,
                                        bn2g, bn2b, bn2m, bn2v, gateW, gateB,
                                        hbuf, gate, N);
    k_pool<<<B, 256, 0, stream>>>(batch, gate, hbuf, hstate, fcW, fcB,
                                  (float*)d_out, N);
}

// Round 11
// 409.377 us; speedup vs baseline: 1.0808x; 1.0556x over previous
//
#include <hip/hip_runtime.h>
#include <cfloat>
#include <cstddef>

constexpr int KIN   = 128;
constexpr int KQD   = 32;
constexpr int KT    = 50;
constexpr int KLH   = 128;
constexpr float BN_EPS = 1e-5f;

typedef __attribute__((ext_vector_type(8))) short bf16x8;
typedef __attribute__((ext_vector_type(4))) float f32x4;
union U8 { bf16x8 v; unsigned u[4]; };

__device__ __forceinline__ float elu_f(float x)  { return x > 0.f ? x : (__expf(x) - 1.f); }
__device__ __forceinline__ float leaky_f(float x){ return x > 0.f ? x : 0.2f * x; }

__device__ __forceinline__ unsigned bfpack(float lo, float hi) {
    unsigned ul = __float_as_uint(lo), uh = __float_as_uint(hi);
    ul += 0x7FFFu + ((ul >> 16) & 1u);
    uh += 0x7FFFu + ((uh >> 16) & 1u);
    return (ul >> 16) | (uh & 0xFFFF0000u);
}
__device__ __forceinline__ unsigned short bf1(float v) {
    unsigned u = __float_as_uint(v);
    u += 0x7FFFu + ((u >> 16) & 1u);
    return (unsigned short)(u >> 16);
}
__device__ __forceinline__ float bflo(unsigned u) { return __uint_as_float(u << 16); }
__device__ __forceinline__ float bfhi(unsigned u) { return __uint_as_float(u & 0xFFFF0000u); }

__device__ __forceinline__ bf16x8 pack8(float4 p, float4 q) {
    U8 t;
    t.u[0] = bfpack(p.x, p.y); t.u[1] = bfpack(p.z, p.w);
    t.u[2] = bfpack(q.x, q.y); t.u[3] = bfpack(q.z, q.w);
    return t.v;
}

// ---------------------------------------------------------------- K1: degree
__global__ void k_deg(const int* __restrict__ ei, int E, int* __restrict__ deg) {
    int e = blockIdx.x * blockDim.x + threadIdx.x;
    if (e < E) atomicAdd(&deg[ei[E + e]], 1);
}

// ---------------- K2a/b/c: hierarchical exclusive scan (parallel)
__global__ __launch_bounds__(1024)
void k_scan_a(const int* __restrict__ deg, int n, int* __restrict__ bsum) {
    __shared__ int wsum[16];
    int tid = threadIdx.x, lane = tid & 63, w = tid >> 6;
    int i0 = blockIdx.x * 4096 + tid * 4;
    int t = 0;
    #pragma unroll
    for (int j = 0; j < 4; j++) t += (i0 + j < n) ? deg[i0 + j] : 0;
    #pragma unroll
    for (int d = 1; d < 64; d <<= 1) t += __shfl_xor(t, d);
    if (lane == 0) wsum[w] = t;
    __syncthreads();
    if (tid == 0) {
        int s = 0;
        #pragma unroll
        for (int k = 0; k < 16; k++) s += wsum[k];
        bsum[blockIdx.x] = s;
    }
}

__global__ void k_scan_b(int* __restrict__ bsum, int nb) {
    if (threadIdx.x == 0) {
        int run = 0;
        for (int i = 0; i < nb; i++) { int v = bsum[i]; bsum[i] = run; run += v; }
    }
}

__global__ __launch_bounds__(1024)
void k_scan_c(const int* __restrict__ deg, int n, const int* __restrict__ bsum,
              int* __restrict__ offsets, int* __restrict__ cursor,
              float* __restrict__ dinv) {
    __shared__ int wsum[16];
    int tid = threadIdx.x, lane = tid & 63, w = tid >> 6;
    int i0 = blockIdx.x * 4096 + tid * 4;
    int v[4];
    #pragma unroll
    for (int j = 0; j < 4; j++) v[j] = (i0 + j < n) ? deg[i0 + j] : 0;
    int tsum = v[0] + v[1] + v[2] + v[3];
    int sc = tsum;
    #pragma unroll
    for (int d = 1; d < 64; d <<= 1) {
        int o = __shfl_up(sc, d);
        if (lane >= d) sc += o;
    }
    if (lane == 63) wsum[w] = sc;
    __syncthreads();
    if (w == 0) {
        int xx = (lane < 16) ? wsum[lane] : 0;
        #pragma unroll
        for (int d = 1; d < 16; d <<= 1) {
            int o = __shfl_up(xx, d);
            if (lane >= d) xx += o;
        }
        if (lane < 16) wsum[lane] = xx;
    }
    __syncthreads();
    int run = bsum[blockIdx.x] + ((w > 0) ? wsum[w - 1] : 0) + sc - tsum;
    #pragma unroll
    for (int j = 0; j < 4; j++) {
        int i = i0 + j;
        if (i < n) {
            cursor[i]      = run;
            offsets[i + 1] = run + v[j];
            dinv[i]        = rsqrtf((float)(v[j] + 1));
            run += v[j];
        }
    }
    if (blockIdx.x == 0 && tid == 0) offsets[0] = 0;
}

// ---------------------------------------------------------------- K3: fill
__global__ void k_fill(const int* __restrict__ ei, int E, int* __restrict__ cursor,
                       int* __restrict__ csr_src) {
    int e = blockIdx.x * blockDim.x + threadIdx.x;
    if (e < E) {
        int s = ei[e], d = ei[E + e];
        int pos = atomicAdd(&cursor[d], 1);
        csr_src[pos] = s;
    }
}

// ------------- K4/K6: MFMA bf16 GEMM  Y[r,:] = X[r,:] @ W,  128x128 weights
template <bool ATT>
__global__ __launch_bounds__(256, 4)
void k_gemm_mfma(const float* __restrict__ X, const float* __restrict__ W,
                 unsigned* __restrict__ Yb, int nrows,
                 const float* __restrict__ attS, const float* __restrict__ attD,
                 float* __restrict__ a_src, float* __restrict__ a_dst) {
    __shared__ float tile[16][132];
    __shared__ float as_sh[128], ad_sh[128];
    int tid  = threadIdx.x;
    int lane = tid & 63;
    int wv   = tid >> 6;
    if (ATT && tid < 128) { as_sh[tid] = attS[tid]; ad_sh[tid] = attD[tid]; }
    int l16 = lane & 15;
    int kq  = (lane >> 4) * 8;
    bf16x8 bfr[2][4];
    #pragma unroll
    for (int nt = 0; nt < 2; nt++) {
        int n = wv * 32 + nt * 16 + l16;
        #pragma unroll
        for (int kk = 0; kk < 4; kk++) {
            int k0 = kk * 32 + kq;
            float f[8];
            #pragma unroll
            for (int j = 0; j < 8; j++) f[j] = W[(size_t)(k0 + j) * 128 + n];
            U8 t;
            t.u[0] = bfpack(f[0], f[1]); t.u[1] = bfpack(f[2], f[3]);
            t.u[2] = bfpack(f[4], f[5]); t.u[3] = bfpack(f[6], f[7]);
            bfr[nt][kk] = t.v;
        }
    }
    int nch = (nrows + 15) / 16;
    for (int ch = blockIdx.x; ch < nch; ch += gridDim.x) {
        int r0 = ch * 16;
        int r  = r0 + l16;
        bool rok = r < nrows;
        const float* xr = X + (size_t)r * 128 + kq;
        float4 z4 = make_float4(0.f, 0.f, 0.f, 0.f);
        bf16x8 afr[4];
        #pragma unroll
        for (int kk = 0; kk < 4; kk++) {
            float4 p = rok ? *reinterpret_cast<const float4*>(xr + kk * 32)     : z4;
            float4 q = rok ? *reinterpret_cast<const float4*>(xr + kk * 32 + 4) : z4;
            afr[kk] = pack8(p, q);
        }
        f32x4 acc0 = {0.f, 0.f, 0.f, 0.f};
        f32x4 acc1 = {0.f, 0.f, 0.f, 0.f};
        #pragma unroll
        for (int kk = 0; kk < 4; kk++) {
            acc0 = __builtin_amdgcn_mfma_f32_16x16x32_bf16(afr[kk], bfr[0][kk], acc0, 0, 0, 0);
            acc1 = __builtin_amdgcn_mfma_f32_16x16x32_bf16(afr[kk], bfr[1][kk], acc1, 0, 0, 0);
        }
        __syncthreads();
        int rowb = (lane >> 4) * 4;
        int cb   = wv * 32 + l16;
        #pragma unroll
        for (int reg = 0; reg < 4; reg++) {
            tile[rowb + reg][cb]      = acc0[reg];
            tile[rowb + reg][cb + 16] = acc1[reg];
        }
        __syncthreads();
        #pragma unroll
        for (int i = 0; i < 4; i++) {
            int idx = tid + i * 256;
            int row = idx >> 6, cp = idx & 63;
            int rr = r0 + row;
            if (rr < nrows) {
                float2 f = *reinterpret_cast<const float2*>(&tile[row][cp * 2]);
                Yb[(size_t)rr * 64 + cp] = bfpack(f.x, f.y);
            }
        }
        if (ATT && tid < 64) {
            int rr2 = tid >> 2, h = tid & 3;
            if (r0 + rr2 < nrows) {
                float ps = 0.f, pd = 0.f;
                #pragma unroll
                for (int j = 0; j < 32; j++) {
                    float v = tile[rr2][h * 32 + j];
                    ps += v * as_sh[h * 32 + j];
                    pd += v * ad_sh[h * 32 + j];
                }
                a_src[(size_t)(r0 + rr2) * 4 + h] = ps;
                a_dst[(size_t)(r0 + rr2) * 4 + h] = pd;
            }
        }
    }
}

// ---------- K5: GAT aggregate — wave/node, alpha in LDS, bf16-pair gather
__global__ __launch_bounds__(256)
void k_gat_agg(const int* __restrict__ offsets, const int* __restrict__ csr_src,
               const float* __restrict__ a_src, const float* __restrict__ a_dst,
               const unsigned* __restrict__ xwb, const float* __restrict__ bias,
               const float* __restrict__ g1, const float* __restrict__ b1,
               const float* __restrict__ mu1, const float* __restrict__ var1,
               float* __restrict__ hout, int n) {
    __shared__ int   src_sh[4][64];
    __shared__ float al_sh[4][4][64];
    int lane = threadIdx.x & 63;
    int wv   = threadIdx.x >> 6;
    int wid  = (blockIdx.x * blockDim.x + threadIdx.x) >> 6;
    int nw   = (gridDim.x * blockDim.x) >> 6;
    int hP   = lane >> 4;
    int c0 = lane * 2, c1 = c0 + 1;
    float bi0 = bias[c0], bi1 = bias[c1];
    float A0 = g1[c0] * rsqrtf(var1[c0] + BN_EPS);
    float A1 = g1[c1] * rsqrtf(var1[c1] + BN_EPS);
    float B0 = b1[c0] - mu1[c0] * A0;
    float B1 = b1[c1] - mu1[c1] * A1;
    for (int node = wid; node < n; node += nw) {
        int beg = offsets[node], end = offsets[node + 1];
        int rowlen = end - beg, total = rowlen + 1;
        float4 adv = *reinterpret_cast<const float4*>(&a_dst[(size_t)node * 4]);
        int sv = (lane < rowlen) ? csr_src[beg + lane] : node;
        float4 as4 = *reinterpret_cast<const float4*>(&a_src[(size_t)sv * 4]);
        float e0 = leaky_f(as4.x + adv.x), e1 = leaky_f(as4.y + adv.y);
        float e2 = leaky_f(as4.z + adv.z), e3 = leaky_f(as4.w + adv.w);
        float m[4] = {-FLT_MAX, -FLT_MAX, -FLT_MAX, -FLT_MAX};
        if (lane < total) { m[0] = e0; m[1] = e1; m[2] = e2; m[3] = e3; }
        for (int i = lane + 64; i < total; i += 64) {
            int src = (i < rowlen) ? csr_src[beg + i] : node;
            float4 a4 = *reinterpret_cast<const float4*>(&a_src[(size_t)src * 4]);
            m[0] = fmaxf(m[0], leaky_f(a4.x + adv.x));
            m[1] = fmaxf(m[1], leaky_f(a4.y + adv.y));
            m[2] = fmaxf(m[2], leaky_f(a4.z + adv.z));
            m[3] = fmaxf(m[3], leaky_f(a4.w + adv.w));
        }
        #pragma unroll
        for (int off = 32; off; off >>= 1) {
            #pragma unroll
            for (int h = 0; h < 4; h++) m[h] = fmaxf(m[h], __shfl_xor(m[h], off));
        }
        float ex[4] = {0.f, 0.f, 0.f, 0.f};
        if (lane < total) {
            ex[0] = __expf(e0 - m[0]); ex[1] = __expf(e1 - m[1]);
            ex[2] = __expf(e2 - m[2]); ex[3] = __expf(e3 - m[3]);
        }
        float s[4] = {ex[0], ex[1], ex[2], ex[3]};
        for (int i = lane + 64; i < total; i += 64) {
            int src = (i < rowlen) ? csr_src[beg + i] : node;
            float4 a4 = *reinterpret_cast<const float4*>(&a_src[(size_t)src * 4]);
            s[0] += __expf(leaky_f(a4.x + adv.x) - m[0]);
            s[1] += __expf(leaky_f(a4.y + adv.y) - m[1]);
            s[2] += __expf(leaky_f(a4.z + adv.z) - m[2]);
            s[3] += __expf(leaky_f(a4.w + adv.w) - m[3]);
        }
        #pragma unroll
        for (int off = 32; off; off >>= 1) {
            #pragma unroll
            for (int h = 0; h < 4; h++) s[h] += __shfl_xor(s[h], off);
        }
        float inv[4];
        #pragma unroll
        for (int h = 0; h < 4; h++) inv[h] = 1.f / (s[h] + 1e-16f);
        src_sh[wv][lane] = sv;
        #pragma unroll
        for (int h = 0; h < 4; h++) al_sh[wv][h][lane] = ex[h] * inv[h];
        __builtin_amdgcn_wave_barrier();
        float acc0 = 0.f, acc1 = 0.f;
        int cnt = min(total, 64);
        {
            int i = 0;
            for (; i + 8 <= cnt; i += 8) {
                int   sj[8]; float aj[8]; unsigned uj[8];
                #pragma unroll
                for (int q = 0; q < 8; q++) { sj[q] = src_sh[wv][i + q]; aj[q] = al_sh[wv][hP][i + q]; }
                #pragma unroll
                for (int q = 0; q < 8; q++) uj[q] = xwb[(size_t)sj[q] * 64 + lane];
                #pragma unroll
                for (int q = 0; q < 8; q++) { acc0 += aj[q] * bflo(uj[q]); acc1 += aj[q] * bfhi(uj[q]); }
            }
            for (; i < cnt; i++) {
                int src  = src_sh[wv][i];
                float aP = al_sh[wv][hP][i];
                unsigned u = xwb[(size_t)src * 64 + lane];
                acc0 += aP * bflo(u);
                acc1 += aP * bfhi(u);
            }
        }
        for (int base = 64; base < total; base += 64) {
            __builtin_amdgcn_wave_barrier();
            int i = base + lane;
            int src2 = node;
            float a0v = 0.f, a1v = 0.f, a2v = 0.f, a3v = 0.f;
            if (i < total) {
                if (i < rowlen) src2 = csr_src[beg + i];
                float4 a4 = *reinterpret_cast<const float4*>(&a_src[(size_t)src2 * 4]);
                a0v = __expf(leaky_f(a4.x + adv.x) - m[0]) * inv[0];
                a1v = __expf(leaky_f(a4.y + adv.y) - m[1]) * inv[1];
                a2v = __expf(leaky_f(a4.z + adv.z) - m[2]) * inv[2];
                a3v = __expf(leaky_f(a4.w + adv.w) - m[3]) * inv[3];
            }
            src_sh[wv][lane] = src2;
            al_sh[wv][0][lane] = a0v; al_sh[wv][1][lane] = a1v;
            al_sh[wv][2][lane] = a2v; al_sh[wv][3][lane] = a3v;
            __builtin_amdgcn_wave_barrier();
            int cnt2 = min(total - base, 64);
            for (int j = 0; j < cnt2; j++) {
                int src  = src_sh[wv][j];
                float aP = al_sh[wv][hP][j];
                unsigned u = xwb[(size_t)src * 64 + lane];
                acc0 += aP * bflo(u);
                acc1 += aP * bfhi(u);
            }
        }
        __builtin_amdgcn_wave_barrier();
        float vA = elu_f(acc0 + bi0);
        float vB = elu_f(acc1 + bi1);
        vA = vA * A0 + B0;
        vB = vB * A1 + B1;
        *reinterpret_cast<float2*>(&hout[(size_t)node * 128 + c0]) =
            make_float2(vA, vB);
    }
}

// ---------- K7: GCN aggregate — wave/node, bf16-pair gather + gate dot
__global__ __launch_bounds__(256)
void k_gcn_agg(const int* __restrict__ offsets, const int* __restrict__ csr_src,
               const float* __restrict__ dinv, const unsigned* __restrict__ hwb,
               const float* __restrict__ bias,
               const float* __restrict__ g2, const float* __restrict__ b2,
               const float* __restrict__ mu2, const float* __restrict__ var2,
               const float* __restrict__ gateW, const float* __restrict__ gateB,
               float* __restrict__ h2, float* __restrict__ gate, int n) {
    __shared__ int   src_sh[4][64];
    __shared__ float w_sh[4][64];
    int lane = threadIdx.x & 63;
    int wv   = threadIdx.x >> 6;
    int wid  = (blockIdx.x * blockDim.x + threadIdx.x) >> 6;
    int nw   = (gridDim.x * blockDim.x) >> 6;
    int c0 = lane * 2, c1 = c0 + 1;
    float bi0 = bias[c0], bi1 = bias[c1];
    float A0 = g2[c0] * rsqrtf(var2[c0] + BN_EPS);
    float A1 = g2[c1] * rsqrtf(var2[c1] + BN_EPS);
    float B0 = b2[c0] - mu2[c0] * A0;
    float B1 = b2[c1] - mu2[c1] * A1;
    float gw0 = gateW[c0], gw1 = gateW[c1], gB = gateB[0];
    for (int node = wid; node < n; node += nw) {
        int beg = offsets[node], end = offsets[node + 1];
        int rowlen = end - beg;
        float dn = dinv[node];
        unsigned us = hwb[(size_t)node * 64 + lane];
        float acc0 = dn * dn * bflo(us);
        float acc1 = dn * dn * bfhi(us);
        for (int base = 0; base < rowlen; base += 64) {
            __builtin_amdgcn_wave_barrier();
            int i = base + lane;
            int src2 = node;
            float wv2 = 0.f;
            if (i < rowlen) { src2 = csr_src[beg + i]; wv2 = dinv[src2] * dn; }
            src_sh[wv][lane] = src2;
            w_sh[wv][lane]   = wv2;
            __builtin_amdgcn_wave_barrier();
            int cnt = min(rowlen - base, 64);
            int j = 0;
            for (; j + 8 <= cnt; j += 8) {
                int   sj[8]; float wj[8]; unsigned uj[8];
                #pragma unroll
                for (int q = 0; q < 8; q++) { sj[q] = src_sh[wv][j + q]; wj[q] = w_sh[wv][j + q]; }
                #pragma unroll
                for (int q = 0; q < 8; q++) uj[q] = hwb[(size_t)sj[q] * 64 + lane];
                #pragma unroll
                for (int q = 0; q < 8; q++) { acc0 += wj[q] * bflo(uj[q]); acc1 += wj[q] * bfhi(uj[q]); }
            }
            for (; j < cnt; j++) {
                int src = src_sh[wv][j];
                float w = w_sh[wv][j];
                unsigned u = hwb[(size_t)src * 64 + lane];
                acc0 += w * bflo(u);
                acc1 += w * bfhi(u);
            }
        }
        __builtin_amdgcn_wave_barrier();
        float vA = elu_f(acc0 + bi0);
        float vB = elu_f(acc1 + bi1);
        vA = vA * A0 + B0;
        vB = vB * A1 + B1;
        *reinterpret_cast<float2*>(&h2[(size_t)node * 128 + c0]) =
            make_float2(vA, vB);
        float p = vA * gw0 + vB * gw1;
        #pragma unroll
        for (int off = 32; off; off >>= 1) p += __shfl_xor(p, off);
        if (lane == 0) gate[node] = p + gB;
    }
}

// -------- K8: GlobalAttention pool + final FC (block per graph)
__device__ __forceinline__ int lbound(const int* a, int n, int key) {
    int lo = 0, hi = n;
    while (lo < hi) { int mid = (lo + hi) >> 1; if (a[mid] < key) lo = mid + 1; else hi = mid; }
    return lo;
}

__global__ __launch_bounds__(256)
void k_pool(const int* __restrict__ batch, const float* __restrict__ gate,
            const float* __restrict__ h2, const float* __restrict__ hT,
            const float* __restrict__ fcW, const float* __restrict__ fcB,
            float* __restrict__ out, int n) {
    int b = blockIdx.x, tid = threadIdx.x;
    __shared__ float red[256];
    __shared__ float sc_sh[256];
    int start = lbound(batch, n, b);
    int end   = lbound(batch, n, b + 1);
    float m = -FLT_MAX;
    for (int i = start + tid; i < end; i += 256) m = fmaxf(m, gate[i]);
    red[tid] = m; __syncthreads();
    for (int s2 = 128; s2 > 0; s2 >>= 1) {
        if (tid < s2) red[tid] = fmaxf(red[tid], red[tid + s2]);
        __syncthreads();
    }
    m = red[0]; __syncthreads();
    float s = 0.f;
    for (int i = start + tid; i < end; i += 256) s += __expf(gate[i] - m);
    red[tid] = s; __syncthreads();
    for (int s2 = 128; s2 > 0; s2 >>= 1) {
        if (tid < s2) red[tid] += red[tid + s2];
        __syncthreads();
    }
    float inv = 1.f / (red[0] + 1e-16f);
    __syncthreads();
    int j = tid & 127, half = tid >> 7;
    float acc = 0.f;
    for (int base = start; base < end; base += 256) {
        int cnt = min(256, end - base);
        __syncthreads();
        if (tid < cnt) sc_sh[tid] = __expf(gate[base + tid] - m) * inv;
        __syncthreads();
        for (int ii = half; ii < cnt; ii += 2)
            acc += sc_sh[ii] * h2[(size_t)(base + ii) * 128 + j];
    }
    red[tid] = acc; __syncthreads();
    if (half == 0) sc_sh[j] = red[j] + red[128 + j];   // graph_rep[b][j]
    __syncthreads();
    float p = 0.f;
    if (tid < 128)
        p = fcW[tid] * sc_sh[tid] + fcW[128 + tid] * hT[(size_t)b * 128 + tid];
    red[tid] = p; __syncthreads();
    for (int s2 = 128; s2 > 0; s2 >>= 1) {
        if (tid < s2) red[tid] += red[tid + s2];
        __syncthreads();
    }
    if (tid == 0) out[b] = red[0] + fcB[0];
}

// ---- K9a: x-projection for all (batch,step): xproj = quant@WihT + bih + bhh,
//      stored pre-swizzled in MFMA accumulator layout.
__global__ __launch_bounds__(256)
void k_xproj(const float* __restrict__ quant, const float* __restrict__ Wih,
             const float* __restrict__ bih, const float* __restrict__ bhh,
             float* __restrict__ xproj) {
    int blk = blockIdx.x;
    int chunk = blk / KT, s = blk % KT;
    int lane = threadIdx.x & 63, w = threadIdx.x >> 6;
    int l15 = lane & 15, kq8 = (lane >> 4) * 8;
    int b = chunk * 16 + l15;
    const float* xr = &quant[(size_t)b * (KT * KQD) + s * KQD + kq8];
    bf16x8 ax = pack8(*reinterpret_cast<const float4*>(xr),
                      *reinterpret_cast<const float4*>(xr + 4));
    #pragma unroll
    for (int ti = 0; ti < 8; ti++) {
        int tc = w * 8 + ti;
        int gcol = w * 128 + ti * 16 + l15;
        const float* wr = &Wih[(size_t)gcol * KQD + kq8];
        bf16x8 bw = pack8(*reinterpret_cast<const float4*>(wr),
                          *reinterpret_cast<const float4*>(wr + 4));
        f32x4 acc = {0.f, 0.f, 0.f, 0.f};
        acc = __builtin_amdgcn_mfma_f32_16x16x32_bf16(ax, bw, acc, 0, 0, 0);
        float bv = bih[gcol] + bhh[gcol];
        acc[0] += bv; acc[1] += bv; acc[2] += bv; acc[3] += bv;
        *reinterpret_cast<f32x4*>(
            &xproj[(((size_t)chunk * KT + s) * 32 + tc) * 256 + lane * 4]) = acc;
    }
}

// ---- K9b: MFMA LSTM. Division-free nonlinearity: combined denominators +
//      raw v_rcp (2 rcp instead of 5 IEEE divides per element — the IEEE
//      div expansion was the VALU bulk at 2 waves/SIMD). xg prefetch issued
//      at TOP of step so the barrier's vmcnt(0) drain doesn't stall on HBM.
__global__ __launch_bounds__(512)
void k_lstm2(const float* __restrict__ xproj, const float* __restrict__ Whh,
             float* __restrict__ hstate) {
    __shared__ unsigned short h16[2][16][148];
    int t = threadIdx.x, lane = t & 63, w = t >> 6;
    int chunk = blockIdx.x;
    int l15 = lane & 15, kq8 = (lane >> 4) * 8;
    int j = w * 16 + l15;
    int rowq = (lane >> 4) * 4;
    bf16x8 whh_f[4][4];
    #pragma unroll
    for (int c = 0; c < 4; c++) {
        int col = c * 128 + j;
        #pragma unroll
        for (int kk = 0; kk < 4; kk++) {
            const float* wr = &Whh[(size_t)col * 128 + kk * 32 + kq8];
            whh_f[c][kk] = pack8(*reinterpret_cast<const float4*>(wr),
                                 *reinterpret_cast<const float4*>(wr + 4));
        }
    }
    for (int p = t; p < 16 * 148; p += 512) {
        int r = p / 148, cc = p - r * 148;
        h16[0][r][cc] = 0;
    }
    float cst[4] = {0.f, 0.f, 0.f, 0.f};
    const float* xb = xproj + ((size_t)chunk * KT) * 32 * 256;
    f32x4 xgA = *reinterpret_cast<const f32x4*>(&xb[(0 * 8 + w) * 256 + lane * 4]);
    f32x4 xgB = *reinterpret_cast<const f32x4*>(&xb[(1 * 8 + w) * 256 + lane * 4]);
    f32x4 xgC = *reinterpret_cast<const f32x4*>(&xb[(2 * 8 + w) * 256 + lane * 4]);
    f32x4 xgD = *reinterpret_cast<const f32x4*>(&xb[(3 * 8 + w) * 256 + lane * 4]);
    int cur = 0;
    __syncthreads();
    for (int s = 0; s < KT; s++) {
        // issue next-step gate inits FIRST: ~full step before use AND before
        // the next barrier's vmcnt(0) drain
        f32x4 nA, nB, nC, nD;
        if (s + 1 < KT) {
            const float* xs = &xb[((size_t)(s + 1) * 32 + w) * 256 + lane * 4];
            nA = *reinterpret_cast<const f32x4*>(&xs[0 * 8 * 256]);
            nB = *reinterpret_cast<const f32x4*>(&xs[1 * 8 * 256]);
            nC = *reinterpret_cast<const f32x4*>(&xs[2 * 8 * 256]);
            nD = *reinterpret_cast<const f32x4*>(&xs[3 * 8 * 256]);
        }
        f32x4 ai = xgA, af = xgB, ag = xgC, ao = xgD;
        #pragma unroll
        for (int kk = 0; kk < 4; kk++) {
            bf16x8 ah = *reinterpret_cast<const bf16x8*>(&h16[cur][l15][kk * 32 + kq8]);
            ai = __builtin_amdgcn_mfma_f32_16x16x32_bf16(ah, whh_f[0][kk], ai, 0, 0, 0);
            af = __builtin_amdgcn_mfma_f32_16x16x32_bf16(ah, whh_f[1][kk], af, 0, 0, 0);
            ag = __builtin_amdgcn_mfma_f32_16x16x32_bf16(ah, whh_f[2][kk], ag, 0, 0, 0);
            ao = __builtin_amdgcn_mfma_f32_16x16x32_bf16(ah, whh_f[3][kk], ao, 0, 0, 0);
        }
        int nxt = cur ^ 1;
        #pragma unroll
        for (int r = 0; r < 4; r++) {
            // sig(i)*tanh(g) + sig(f)*c with ONE rcp:
            //   c' = [c*(1+e^-i)(e^2g+1) + (e^2g-1)(1+e^-f)] / [(1+e^-f)(1+e^-i)(e^2g+1)]
            float eiv = __expf(fminf(-ai[r], 25.f));
            float efv = __expf(fminf(-af[r], 25.f));
            float egv = __expf(fminf(2.f * ag[r], 50.f));
            float eov = __expf(fminf(-ao[r], 25.f));
            float pi = 1.f + eiv, pf = 1.f + efv;
            float gp = egv + 1.f, gm = egv - 1.f;
            float P  = pi * gp;
            float D  = pf * P;
            float cn = fmaf(cst[r], P, gm * pf) * __builtin_amdgcn_rcpf(D);
            cst[r] = cn;
            // h = sig(o)*tanh(c') with ONE rcp
            float ecv = __expf(fminf(2.f * cn, 50.f));
            float D2  = (1.f + eov) * (ecv + 1.f);
            float hv  = (ecv - 1.f) * __builtin_amdgcn_rcpf(D2);
            h16[nxt][rowq + r][j] = bf1(hv);
        }
        xgA = nA; xgB = nB; xgC = nC; xgD = nD;
        __syncthreads();
        cur = nxt;
    }
    int b0 = chunk * 16;
    for (int p = t; p < 16 * KLH; p += 512) {
        int row = p >> 7, jj = p & 127;
        hstate[(size_t)(b0 + row) * KLH + jj] =
            __uint_as_float((unsigned)h16[cur][row][jj] << 16);
    }
}

// ----------------------------------------------------------------- launcher
extern "C" void kernel_launch(void* const* d_in, const int* in_sizes, int n_in,
                              void* d_out, int out_size, void* d_ws, size_t ws_size,
                              hipStream_t stream) {
    const float* x     = (const float*)d_in[0];
    const int*   ei    = (const int*)  d_in[1];
    const int*   batch = (const int*)  d_in[2];
    const float* quant = (const float*)d_in[3];
    const float* gatW  = (const float*)d_in[4];
    const float* attS  = (const float*)d_in[5];
    const float* attD  = (const float*)d_in[6];
    const float* gatB  = (const float*)d_in[7];
    const float* bn1g  = (const float*)d_in[8];
    const float* bn1b  = (const float*)d_in[9];
    const float* bn1m  = (const float*)d_in[10];
    const float* bn1v  = (const float*)d_in[11];
    const float* gcnW  = (const float*)d_in[12];
    const float* gcnB  = (const float*)d_in[13];
    const float* bn2g  = (const float*)d_in[14];
    const float* bn2b  = (const float*)d_in[15];
    const float* bn2m  = (const float*)d_in[16];
    const float* bn2v  = (const float*)d_in[17];
    const float* gateW = (const float*)d_in[18];
    const float* gateB = (const float*)d_in[19];
    const float* Wih   = (const float*)d_in[20];
    const float* Whh   = (const float*)d_in[21];
    const float* bih   = (const float*)d_in[22];
    const float* bhh   = (const float*)d_in[23];
    const float* fcW   = (const float*)d_in[24];
    const float* fcB   = (const float*)d_in[25];

    int N = in_sizes[0] / KIN;
    int E = in_sizes[1] / 2;
    int B = in_sizes[3] / (KT * KQD);
    int nchunks = B / 16;

    char* ws = (char*)d_ws;
    size_t off = 0;
    auto alloc = [&](size_t bytes) -> void* {
        void* p = ws + off;
        off += (bytes + 511) & ~(size_t)511;
        return p;
    };
    int nb = (N + 4095) / 4096;
    int*      deg     = (int*)     alloc((size_t)N * 4);
    int*      offsets = (int*)     alloc((size_t)(N + 1) * 4);
    int*      cursor  = (int*)     alloc((size_t)N * 4);
    float*    dinv    = (float*)   alloc((size_t)N * 4);
    int*      csr_src = (int*)     alloc((size_t)E * 4);
    int*      bsum    = (int*)     alloc((size_t)nb * 4);
    float*    a_src   = (float*)   alloc((size_t)N * 16);
    float*    a_dst   = (float*)   alloc((size_t)N * 16);
    unsigned* xwb     = (unsigned*)alloc((size_t)N * 256);
    float*    hbuf    = (float*)   alloc((size_t)N * 512);
    float*    gate    = (float*)   alloc((size_t)N * 4);
    float*    hstate  = (float*)   alloc((size_t)B * KLH * 4);
    float*    xproj   = (float*)   alloc((size_t)nchunks * KT * 32 * 256 * 4);

    hipMemsetAsync(deg, 0, (size_t)N * 4, stream);
    int eb = (E + 255) / 256;
    k_deg   <<<eb, 256, 0, stream>>>(ei, E, deg);
    k_scan_a<<<nb, 1024, 0, stream>>>(deg, N, bsum);
    k_scan_b<<<1, 64, 0, stream>>>(bsum, nb);
    k_scan_c<<<nb, 1024, 0, stream>>>(deg, N, bsum, offsets, cursor, dinv);
    k_fill  <<<eb, 256, 0, stream>>>(ei, E, cursor, csr_src);

    k_xproj<<<nchunks * KT, 256, 0, stream>>>(quant, Wih, bih, bhh, xproj);
    k_lstm2<<<nchunks, 512, 0, stream>>>(xproj, Whh, hstate);

    k_gemm_mfma<true ><<<1024, 256, 0, stream>>>(x, gatW, xwb, N, attS, attD, a_src, a_dst);
    k_gat_agg<<<3072, 256, 0, stream>>>(offsets, csr_src, a_src, a_dst, xwb, gatB,
                                        bn1g, bn1b, bn1m, bn1v, hbuf, N);
    k_gemm_mfma<false><<<1024, 256, 0, stream>>>(hbuf, gcnW, xwb, N,
                                                 nullptr, nullptr, nullptr, nullptr);
    k_gcn_agg<<<3072, 256, 0, stream>>>(offsets, csr_src, dinv, xwb, gcnB,
                                        bn2g, bn2b, bn2m, bn2v, gateW, gateB,
                                        hbuf, gate, N);
    k_pool<<<B, 256, 0, stream>>>(batch, gate, hbuf, hstate, fcW, fcB,
                                  (float*)d_out, N);
}

// Round 12
// 385.275 us; speedup vs baseline: 1.1484x; 1.0626x over previous
//
#include <hip/hip_runtime.h>
#include <cfloat>
#include <cstddef>

constexpr int KIN   = 128;
constexpr int KQD   = 32;
constexpr int KT    = 50;
constexpr int KLH   = 128;
constexpr float BN_EPS = 1e-5f;

typedef __attribute__((ext_vector_type(8))) short bf16x8;
typedef __attribute__((ext_vector_type(4))) float f32x4;
union U8 { bf16x8 v; unsigned u[4]; };

__device__ __forceinline__ float elu_f(float x)  { return x > 0.f ? x : (__expf(x) - 1.f); }
__device__ __forceinline__ float leaky_f(float x){ return x > 0.f ? x : 0.2f * x; }

__device__ __forceinline__ unsigned bfpack(float lo, float hi) {
    unsigned ul = __float_as_uint(lo), uh = __float_as_uint(hi);
    ul += 0x7FFFu + ((ul >> 16) & 1u);
    uh += 0x7FFFu + ((uh >> 16) & 1u);
    return (ul >> 16) | (uh & 0xFFFF0000u);
}
__device__ __forceinline__ unsigned short bf1(float v) {
    unsigned u = __float_as_uint(v);
    u += 0x7FFFu + ((u >> 16) & 1u);
    return (unsigned short)(u >> 16);
}
__device__ __forceinline__ float bflo(unsigned u) { return __uint_as_float(u << 16); }
__device__ __forceinline__ float bfhi(unsigned u) { return __uint_as_float(u & 0xFFFF0000u); }

__device__ __forceinline__ bf16x8 pack8(float4 p, float4 q) {
    U8 t;
    t.u[0] = bfpack(p.x, p.y); t.u[1] = bfpack(p.z, p.w);
    t.u[2] = bfpack(q.x, q.y); t.u[3] = bfpack(q.z, q.w);
    return t.v;
}

// ---------------------------------------------------------------- K1: degree
__global__ void k_deg(const int* __restrict__ ei, int E, int* __restrict__ deg) {
    int e = blockIdx.x * blockDim.x + threadIdx.x;
    if (e < E) atomicAdd(&deg[ei[E + e]], 1);
}

// ---------------- K2a/b/c: hierarchical exclusive scan (parallel)
__global__ __launch_bounds__(1024)
void k_scan_a(const int* __restrict__ deg, int n, int* __restrict__ bsum) {
    __shared__ int wsum[16];
    int tid = threadIdx.x, lane = tid & 63, w = tid >> 6;
    int i0 = blockIdx.x * 4096 + tid * 4;
    int t = 0;
    #pragma unroll
    for (int j = 0; j < 4; j++) t += (i0 + j < n) ? deg[i0 + j] : 0;
    #pragma unroll
    for (int d = 1; d < 64; d <<= 1) t += __shfl_xor(t, d);
    if (lane == 0) wsum[w] = t;
    __syncthreads();
    if (tid == 0) {
        int s = 0;
        #pragma unroll
        for (int k = 0; k < 16; k++) s += wsum[k];
        bsum[blockIdx.x] = s;
    }
}

__global__ void k_scan_b(int* __restrict__ bsum, int nb) {
    if (threadIdx.x == 0) {
        int run = 0;
        for (int i = 0; i < nb; i++) { int v = bsum[i]; bsum[i] = run; run += v; }
    }
}

__global__ __launch_bounds__(1024)
void k_scan_c(const int* __restrict__ deg, int n, const int* __restrict__ bsum,
              int* __restrict__ offsets, int* __restrict__ cursor,
              float* __restrict__ dinv) {
    __shared__ int wsum[16];
    int tid = threadIdx.x, lane = tid & 63, w = tid >> 6;
    int i0 = blockIdx.x * 4096 + tid * 4;
    int v[4];
    #pragma unroll
    for (int j = 0; j < 4; j++) v[j] = (i0 + j < n) ? deg[i0 + j] : 0;
    int tsum = v[0] + v[1] + v[2] + v[3];
    int sc = tsum;
    #pragma unroll
    for (int d = 1; d < 64; d <<= 1) {
        int o = __shfl_up(sc, d);
        if (lane >= d) sc += o;
    }
    if (lane == 63) wsum[w] = sc;
    __syncthreads();
    if (w == 0) {
        int xx = (lane < 16) ? wsum[lane] : 0;
        #pragma unroll
        for (int d = 1; d < 16; d <<= 1) {
            int o = __shfl_up(xx, d);
            if (lane >= d) xx += o;
        }
        if (lane < 16) wsum[lane] = xx;
    }
    __syncthreads();
    int run = bsum[blockIdx.x] + ((w > 0) ? wsum[w - 1] : 0) + sc - tsum;
    #pragma unroll
    for (int j = 0; j < 4; j++) {
        int i = i0 + j;
        if (i < n) {
            cursor[i]      = run;
            offsets[i + 1] = run + v[j];
            dinv[i]        = rsqrtf((float)(v[j] + 1));
            run += v[j];
        }
    }
    if (blockIdx.x == 0 && tid == 0) offsets[0] = 0;
}

// ------------- K4/K6: MFMA bf16 GEMM (256-thr standalone, used for gemm2)
template <bool ATT>
__global__ __launch_bounds__(256, 4)
void k_gemm_mfma(const float* __restrict__ X, const float* __restrict__ W,
                 unsigned* __restrict__ Yb, int nrows,
                 const float* __restrict__ attS, const float* __restrict__ attD,
                 float* __restrict__ a_src, float* __restrict__ a_dst) {
    __shared__ float tile[16][132];
    __shared__ float as_sh[128], ad_sh[128];
    int tid  = threadIdx.x;
    int lane = tid & 63;
    int wv   = tid >> 6;
    if (ATT && tid < 128) { as_sh[tid] = attS[tid]; ad_sh[tid] = attD[tid]; }
    int l16 = lane & 15;
    int kq  = (lane >> 4) * 8;
    bf16x8 bfr[2][4];
    #pragma unroll
    for (int nt = 0; nt < 2; nt++) {
        int n = wv * 32 + nt * 16 + l16;
        #pragma unroll
        for (int kk = 0; kk < 4; kk++) {
            int k0 = kk * 32 + kq;
            float f[8];
            #pragma unroll
            for (int j = 0; j < 8; j++) f[j] = W[(size_t)(k0 + j) * 128 + n];
            U8 t;
            t.u[0] = bfpack(f[0], f[1]); t.u[1] = bfpack(f[2], f[3]);
            t.u[2] = bfpack(f[4], f[5]); t.u[3] = bfpack(f[6], f[7]);
            bfr[nt][kk] = t.v;
        }
    }
    int nch = (nrows + 15) / 16;
    for (int ch = blockIdx.x; ch < nch; ch += gridDim.x) {
        int r0 = ch * 16;
        int r  = r0 + l16;
        bool rok = r < nrows;
        const float* xr = X + (size_t)r * 128 + kq;
        float4 z4 = make_float4(0.f, 0.f, 0.f, 0.f);
        bf16x8 afr[4];
        #pragma unroll
        for (int kk = 0; kk < 4; kk++) {
            float4 p = rok ? *reinterpret_cast<const float4*>(xr + kk * 32)     : z4;
            float4 q = rok ? *reinterpret_cast<const float4*>(xr + kk * 32 + 4) : z4;
            afr[kk] = pack8(p, q);
        }
        f32x4 acc0 = {0.f, 0.f, 0.f, 0.f};
        f32x4 acc1 = {0.f, 0.f, 0.f, 0.f};
        #pragma unroll
        for (int kk = 0; kk < 4; kk++) {
            acc0 = __builtin_amdgcn_mfma_f32_16x16x32_bf16(afr[kk], bfr[0][kk], acc0, 0, 0, 0);
            acc1 = __builtin_amdgcn_mfma_f32_16x16x32_bf16(afr[kk], bfr[1][kk], acc1, 0, 0, 0);
        }
        __syncthreads();
        int rowb = (lane >> 4) * 4;
        int cb   = wv * 32 + l16;
        #pragma unroll
        for (int reg = 0; reg < 4; reg++) {
            tile[rowb + reg][cb]      = acc0[reg];
            tile[rowb + reg][cb + 16] = acc1[reg];
        }
        __syncthreads();
        #pragma unroll
        for (int i = 0; i < 4; i++) {
            int idx = tid + i * 256;
            int row = idx >> 6, cp = idx & 63;
            int rr = r0 + row;
            if (rr < nrows) {
                float2 f = *reinterpret_cast<const float2*>(&tile[row][cp * 2]);
                Yb[(size_t)rr * 64 + cp] = bfpack(f.x, f.y);
            }
        }
        if (ATT && tid < 64) {
            int rr2 = tid >> 2, h = tid & 3;
            if (r0 + rr2 < nrows) {
                float ps = 0.f, pd = 0.f;
                #pragma unroll
                for (int j = 0; j < 32; j++) {
                    float v = tile[rr2][h * 32 + j];
                    ps += v * as_sh[h * 32 + j];
                    pd += v * ad_sh[h * 32 + j];
                }
                a_src[(size_t)(r0 + rr2) * 4 + h] = ps;
                a_dst[(size_t)(r0 + rr2) * 4 + h] = pd;
            }
        }
    }
}

// ---------- K5: GAT aggregate — wave/node, alpha in LDS, bf16-pair gather
__global__ __launch_bounds__(256)
void k_gat_agg(const int* __restrict__ offsets, const int* __restrict__ csr_src,
               const float* __restrict__ a_src, const float* __restrict__ a_dst,
               const unsigned* __restrict__ xwb, const float* __restrict__ bias,
               const float* __restrict__ g1, const float* __restrict__ b1,
               const float* __restrict__ mu1, const float* __restrict__ var1,
               float* __restrict__ hout, int n) {
    __shared__ int   src_sh[4][64];
    __shared__ float al_sh[4][4][64];
    int lane = threadIdx.x & 63;
    int wv   = threadIdx.x >> 6;
    int wid  = (blockIdx.x * blockDim.x + threadIdx.x) >> 6;
    int nw   = (gridDim.x * blockDim.x) >> 6;
    int hP   = lane >> 4;
    int c0 = lane * 2, c1 = c0 + 1;
    float bi0 = bias[c0], bi1 = bias[c1];
    float A0 = g1[c0] * rsqrtf(var1[c0] + BN_EPS);
    float A1 = g1[c1] * rsqrtf(var1[c1] + BN_EPS);
    float B0 = b1[c0] - mu1[c0] * A0;
    float B1 = b1[c1] - mu1[c1] * A1;
    for (int node = wid; node < n; node += nw) {
        int beg = offsets[node], end = offsets[node + 1];
        int rowlen = end - beg, total = rowlen + 1;
        float4 adv = *reinterpret_cast<const float4*>(&a_dst[(size_t)node * 4]);
        int sv = (lane < rowlen) ? csr_src[beg + lane] : node;
        float4 as4 = *reinterpret_cast<const float4*>(&a_src[(size_t)sv * 4]);
        float e0 = leaky_f(as4.x + adv.x), e1 = leaky_f(as4.y + adv.y);
        float e2 = leaky_f(as4.z + adv.z), e3 = leaky_f(as4.w + adv.w);
        float m[4] = {-FLT_MAX, -FLT_MAX, -FLT_MAX, -FLT_MAX};
        if (lane < total) { m[0] = e0; m[1] = e1; m[2] = e2; m[3] = e3; }
        for (int i = lane + 64; i < total; i += 64) {
            int src = (i < rowlen) ? csr_src[beg + i] : node;
            float4 a4 = *reinterpret_cast<const float4*>(&a_src[(size_t)src * 4]);
            m[0] = fmaxf(m[0], leaky_f(a4.x + adv.x));
            m[1] = fmaxf(m[1], leaky_f(a4.y + adv.y));
            m[2] = fmaxf(m[2], leaky_f(a4.z + adv.z));
            m[3] = fmaxf(m[3], leaky_f(a4.w + adv.w));
        }
        #pragma unroll
        for (int off = 32; off; off >>= 1) {
            #pragma unroll
            for (int h = 0; h < 4; h++) m[h] = fmaxf(m[h], __shfl_xor(m[h], off));
        }
        float ex[4] = {0.f, 0.f, 0.f, 0.f};
        if (lane < total) {
            ex[0] = __expf(e0 - m[0]); ex[1] = __expf(e1 - m[1]);
            ex[2] = __expf(e2 - m[2]); ex[3] = __expf(e3 - m[3]);
        }
        float s[4] = {ex[0], ex[1], ex[2], ex[3]};
        for (int i = lane + 64; i < total; i += 64) {
            int src = (i < rowlen) ? csr_src[beg + i] : node;
            float4 a4 = *reinterpret_cast<const float4*>(&a_src[(size_t)src * 4]);
            s[0] += __expf(leaky_f(a4.x + adv.x) - m[0]);
            s[1] += __expf(leaky_f(a4.y + adv.y) - m[1]);
            s[2] += __expf(leaky_f(a4.z + adv.z) - m[2]);
            s[3] += __expf(leaky_f(a4.w + adv.w) - m[3]);
        }
        #pragma unroll
        for (int off = 32; off; off >>= 1) {
            #pragma unroll
            for (int h = 0; h < 4; h++) s[h] += __shfl_xor(s[h], off);
        }
        float inv[4];
        #pragma unroll
        for (int h = 0; h < 4; h++) inv[h] = 1.f / (s[h] + 1e-16f);
        src_sh[wv][lane] = sv;
        #pragma unroll
        for (int h = 0; h < 4; h++) al_sh[wv][h][lane] = ex[h] * inv[h];
        __builtin_amdgcn_wave_barrier();
        float acc0 = 0.f, acc1 = 0.f;
        int cnt = min(total, 64);
        {
            int i = 0;
            for (; i + 8 <= cnt; i += 8) {
                int   sj[8]; float aj[8]; unsigned uj[8];
                #pragma unroll
                for (int q = 0; q < 8; q++) { sj[q] = src_sh[wv][i + q]; aj[q] = al_sh[wv][hP][i + q]; }
                #pragma unroll
                for (int q = 0; q < 8; q++) uj[q] = xwb[(size_t)sj[q] * 64 + lane];
                #pragma unroll
                for (int q = 0; q < 8; q++) { acc0 += aj[q] * bflo(uj[q]); acc1 += aj[q] * bfhi(uj[q]); }
            }
            for (; i < cnt; i++) {
                int src  = src_sh[wv][i];
                float aP = al_sh[wv][hP][i];
                unsigned u = xwb[(size_t)src * 64 + lane];
                acc0 += aP * bflo(u);
                acc1 += aP * bfhi(u);
            }
        }
        for (int base = 64; base < total; base += 64) {
            __builtin_amdgcn_wave_barrier();
            int i = base + lane;
            int src2 = node;
            float a0v = 0.f, a1v = 0.f, a2v = 0.f, a3v = 0.f;
            if (i < total) {
                if (i < rowlen) src2 = csr_src[beg + i];
                float4 a4 = *reinterpret_cast<const float4*>(&a_src[(size_t)src2 * 4]);
                a0v = __expf(leaky_f(a4.x + adv.x) - m[0]) * inv[0];
                a1v = __expf(leaky_f(a4.y + adv.y) - m[1]) * inv[1];
                a2v = __expf(leaky_f(a4.z + adv.z) - m[2]) * inv[2];
                a3v = __expf(leaky_f(a4.w + adv.w) - m[3]) * inv[3];
            }
            src_sh[wv][lane] = src2;
            al_sh[wv][0][lane] = a0v; al_sh[wv][1][lane] = a1v;
            al_sh[wv][2][lane] = a2v; al_sh[wv][3][lane] = a3v;
            __builtin_amdgcn_wave_barrier();
            int cnt2 = min(total - base, 64);
            for (int j = 0; j < cnt2; j++) {
                int src  = src_sh[wv][j];
                float aP = al_sh[wv][hP][j];
                unsigned u = xwb[(size_t)src * 64 + lane];
                acc0 += aP * bflo(u);
                acc1 += aP * bfhi(u);
            }
        }
        __builtin_amdgcn_wave_barrier();
        float vA = elu_f(acc0 + bi0);
        float vB = elu_f(acc1 + bi1);
        vA = vA * A0 + B0;
        vB = vB * A1 + B1;
        *reinterpret_cast<float2*>(&hout[(size_t)node * 128 + c0]) =
            make_float2(vA, vB);
    }
}

// ---------- K7: GCN aggregate — wave/node, bf16-pair gather + gate dot
__global__ __launch_bounds__(256)
void k_gcn_agg(const int* __restrict__ offsets, const int* __restrict__ csr_src,
               const float* __restrict__ dinv, const unsigned* __restrict__ hwb,
               const float* __restrict__ bias,
               const float* __restrict__ g2, const float* __restrict__ b2,
               const float* __restrict__ mu2, const float* __restrict__ var2,
               const float* __restrict__ gateW, const float* __restrict__ gateB,
               float* __restrict__ h2, float* __restrict__ gate, int n) {
    __shared__ int   src_sh[4][64];
    __shared__ float w_sh[4][64];
    int lane = threadIdx.x & 63;
    int wv   = threadIdx.x >> 6;
    int wid  = (blockIdx.x * blockDim.x + threadIdx.x) >> 6;
    int nw   = (gridDim.x * blockDim.x) >> 6;
    int c0 = lane * 2, c1 = c0 + 1;
    float bi0 = bias[c0], bi1 = bias[c1];
    float A0 = g2[c0] * rsqrtf(var2[c0] + BN_EPS);
    float A1 = g2[c1] * rsqrtf(var2[c1] + BN_EPS);
    float B0 = b2[c0] - mu2[c0] * A0;
    float B1 = b2[c1] - mu2[c1] * A1;
    float gw0 = gateW[c0], gw1 = gateW[c1], gB = gateB[0];
    for (int node = wid; node < n; node += nw) {
        int beg = offsets[node], end = offsets[node + 1];
        int rowlen = end - beg;
        float dn = dinv[node];
        unsigned us = hwb[(size_t)node * 64 + lane];
        float acc0 = dn * dn * bflo(us);
        float acc1 = dn * dn * bfhi(us);
        for (int base = 0; base < rowlen; base += 64) {
            __builtin_amdgcn_wave_barrier();
            int i = base + lane;
            int src2 = node;
            float wv2 = 0.f;
            if (i < rowlen) { src2 = csr_src[beg + i]; wv2 = dinv[src2] * dn; }
            src_sh[wv][lane] = src2;
            w_sh[wv][lane]   = wv2;
            __builtin_amdgcn_wave_barrier();
            int cnt = min(rowlen - base, 64);
            int j = 0;
            for (; j + 8 <= cnt; j += 8) {
                int   sj[8]; float wj[8]; unsigned uj[8];
                #pragma unroll
                for (int q = 0; q < 8; q++) { sj[q] = src_sh[wv][j + q]; wj[q] = w_sh[wv][j + q]; }
                #pragma unroll
                for (int q = 0; q < 8; q++) uj[q] = hwb[(size_t)sj[q] * 64 + lane];
                #pragma unroll
                for (int q = 0; q < 8; q++) { acc0 += wj[q] * bflo(uj[q]); acc1 += wj[q] * bfhi(uj[q]); }
            }
            for (; j < cnt; j++) {
                int src = src_sh[wv][j];
                float w = w_sh[wv][j];
                unsigned u = hwb[(size_t)src * 64 + lane];
                acc0 += w * bflo(u);
                acc1 += w * bfhi(u);
            }
        }
        __builtin_amdgcn_wave_barrier();
        float vA = elu_f(acc0 + bi0);
        float vB = elu_f(acc1 + bi1);
        vA = vA * A0 + B0;
        vB = vB * A1 + B1;
        *reinterpret_cast<float2*>(&h2[(size_t)node * 128 + c0]) =
            make_float2(vA, vB);
        float p = vA * gw0 + vB * gw1;
        #pragma unroll
        for (int off = 32; off; off >>= 1) p += __shfl_xor(p, off);
        if (lane == 0) gate[node] = p + gB;
    }
}

// -------- K8: GlobalAttention pool + final FC (block per graph)
__device__ __forceinline__ int lbound(const int* a, int n, int key) {
    int lo = 0, hi = n;
    while (lo < hi) { int mid = (lo + hi) >> 1; if (a[mid] < key) lo = mid + 1; else hi = mid; }
    return lo;
}

__global__ __launch_bounds__(256)
void k_pool(const int* __restrict__ batch, const float* __restrict__ gate,
            const float* __restrict__ h2, const float* __restrict__ hT,
            const float* __restrict__ fcW, const float* __restrict__ fcB,
            float* __restrict__ out, int n) {
    int b = blockIdx.x, tid = threadIdx.x;
    __shared__ float red[256];
    __shared__ float sc_sh[256];
    int start = lbound(batch, n, b);
    int end   = lbound(batch, n, b + 1);
    float m = -FLT_MAX;
    for (int i = start + tid; i < end; i += 256) m = fmaxf(m, gate[i]);
    red[tid] = m; __syncthreads();
    for (int s2 = 128; s2 > 0; s2 >>= 1) {
        if (tid < s2) red[tid] = fmaxf(red[tid], red[tid + s2]);
        __syncthreads();
    }
    m = red[0]; __syncthreads();
    float s = 0.f;
    for (int i = start + tid; i < end; i += 256) s += __expf(gate[i] - m);
    red[tid] = s; __syncthreads();
    for (int s2 = 128; s2 > 0; s2 >>= 1) {
        if (tid < s2) red[tid] += red[tid + s2];
        __syncthreads();
    }
    float inv = 1.f / (red[0] + 1e-16f);
    __syncthreads();
    int j = tid & 127, half = tid >> 7;
    float acc = 0.f;
    for (int base = start; base < end; base += 256) {
        int cnt = min(256, end - base);
        __syncthreads();
        if (tid < cnt) sc_sh[tid] = __expf(gate[base + tid] - m) * inv;
        __syncthreads();
        for (int ii = half; ii < cnt; ii += 2)
            acc += sc_sh[ii] * h2[(size_t)(base + ii) * 128 + j];
    }
    red[tid] = acc; __syncthreads();
    if (half == 0) sc_sh[j] = red[j] + red[128 + j];   // graph_rep[b][j]
    __syncthreads();
    float p = 0.f;
    if (tid < 128)
        p = fcW[tid] * sc_sh[tid] + fcW[128 + tid] * hT[(size_t)b * 128 + tid];
    red[tid] = p; __syncthreads();
    for (int s2 = 128; s2 > 0; s2 >>= 1) {
        if (tid < s2) red[tid] += red[tid + s2];
        __syncthreads();
    }
    if (tid == 0) out[b] = red[0] + fcB[0];
}

// ---- K9a: x-projection for all (batch,step), MFMA-accumulator layout
__global__ __launch_bounds__(256)
void k_xproj(const float* __restrict__ quant, const float* __restrict__ Wih,
             const float* __restrict__ bih, const float* __restrict__ bhh,
             float* __restrict__ xproj) {
    int blk = blockIdx.x;
    int chunk = blk / KT, s = blk % KT;
    int lane = threadIdx.x & 63, w = threadIdx.x >> 6;
    int l15 = lane & 15, kq8 = (lane >> 4) * 8;
    int b = chunk * 16 + l15;
    const float* xr = &quant[(size_t)b * (KT * KQD) + s * KQD + kq8];
    bf16x8 ax = pack8(*reinterpret_cast<const float4*>(xr),
                      *reinterpret_cast<const float4*>(xr + 4));
    #pragma unroll
    for (int ti = 0; ti < 8; ti++) {
        int tc = w * 8 + ti;
        int gcol = w * 128 + ti * 16 + l15;
        const float* wr = &Wih[(size_t)gcol * KQD + kq8];
        bf16x8 bw = pack8(*reinterpret_cast<const float4*>(wr),
                          *reinterpret_cast<const float4*>(wr + 4));
        f32x4 acc = {0.f, 0.f, 0.f, 0.f};
        acc = __builtin_amdgcn_mfma_f32_16x16x32_bf16(ax, bw, acc, 0, 0, 0);
        float bv = bih[gcol] + bhh[gcol];
        acc[0] += bv; acc[1] += bv; acc[2] += bv; acc[3] += bv;
        *reinterpret_cast<f32x4*>(
            &xproj[(((size_t)chunk * KT + s) * 32 + tc) * 256 + lane * 4]) = acc;
    }
}

// ---- K-FUSED: three independent paths in one launch so the serial LSTM
//      (16 blocks), the scatter-bound fill (latency-bound), and the
//      compute-bound GAT gemm overlap instead of serializing:
//      blocks [0,nchunks)                 -> LSTM (dispatched first)
//      blocks [nchunks, nchunks+ngemm)    -> gemm1 (x@gatW + att dots), 8-wave
//      blocks [nchunks+ngemm, ...)        -> csr fill (1 edge/thread)
struct GemmSh { float tile[16][132]; float as[128]; float ad[128]; };
struct LstmSh { unsigned short h16[2][16][148]; };
union  FusedSh { GemmSh g; LstmSh l; };

__global__ __launch_bounds__(512)
void k_fused(// lstm
             const float* __restrict__ xproj, const float* __restrict__ Whh,
             float* __restrict__ hstate, int nchunks,
             // gemm1
             const float* __restrict__ X, const float* __restrict__ W,
             unsigned* __restrict__ Yb, int nrows,
             const float* __restrict__ attS, const float* __restrict__ attD,
             float* __restrict__ a_src, float* __restrict__ a_dst, int ngemm,
             // fill
             const int* __restrict__ ei, int E, int* __restrict__ cursor,
             int* __restrict__ csr_src) {
    __shared__ FusedSh sh;
    int bid = (int)blockIdx.x;
    int t = threadIdx.x, lane = t & 63, w = t >> 6;

    if (bid >= nchunks + ngemm) {
        // ---------------- fill path (no LDS, ~8 VGPR)
        int e = (bid - nchunks - ngemm) * 512 + t;
        if (e < E) {
            int s = ei[e], d = ei[E + e];
            int pos = atomicAdd(&cursor[d], 1);
            csr_src[pos] = s;
        }
        return;
    }

    int l15 = lane & 15, kq8 = (lane >> 4) * 8;

    if (bid >= nchunks) {
        // ---------------- gemm1 path: 8 waves, wave w owns cols [16w,16w+16)
        if (t < 128) { sh.g.as[t] = attS[t]; sh.g.ad[t] = attD[t]; }
        int n = w * 16 + l15;
        bf16x8 bfr[4];
        #pragma unroll
        for (int kk = 0; kk < 4; kk++) {
            int k0 = kk * 32 + kq8;
            float f[8];
            #pragma unroll
            for (int jj = 0; jj < 8; jj++) f[jj] = W[(size_t)(k0 + jj) * 128 + n];
            U8 tp;
            tp.u[0] = bfpack(f[0], f[1]); tp.u[1] = bfpack(f[2], f[3]);
            tp.u[2] = bfpack(f[4], f[5]); tp.u[3] = bfpack(f[6], f[7]);
            bfr[kk] = tp.v;
        }
        int nch = (nrows + 15) / 16;
        for (int ch = bid - nchunks; ch < nch; ch += ngemm) {
            int r0 = ch * 16;
            int r  = r0 + l15;
            bool rok = r < nrows;
            const float* xr = X + (size_t)r * 128 + kq8;
            float4 z4 = make_float4(0.f, 0.f, 0.f, 0.f);
            bf16x8 afr[4];
            #pragma unroll
            for (int kk = 0; kk < 4; kk++) {
                float4 p = rok ? *reinterpret_cast<const float4*>(xr + kk * 32)     : z4;
                float4 q = rok ? *reinterpret_cast<const float4*>(xr + kk * 32 + 4) : z4;
                afr[kk] = pack8(p, q);
            }
            f32x4 acc = {0.f, 0.f, 0.f, 0.f};
            #pragma unroll
            for (int kk = 0; kk < 4; kk++)
                acc = __builtin_amdgcn_mfma_f32_16x16x32_bf16(afr[kk], bfr[kk], acc, 0, 0, 0);
            __syncthreads();
            int rowb = (lane >> 4) * 4;
            #pragma unroll
            for (int reg = 0; reg < 4; reg++)
                sh.g.tile[rowb + reg][n] = acc[reg];
            __syncthreads();
            #pragma unroll
            for (int i = 0; i < 2; i++) {
                int idx = t + i * 512;
                int row = idx >> 6, cp = idx & 63;
                int rr = r0 + row;
                if (rr < nrows) {
                    float2 f = *reinterpret_cast<const float2*>(&sh.g.tile[row][cp * 2]);
                    Yb[(size_t)rr * 64 + cp] = bfpack(f.x, f.y);
                }
            }
            if (t < 64) {
                int rr2 = t >> 2, h = t & 3;
                if (r0 + rr2 < nrows) {
                    float ps = 0.f, pd = 0.f;
                    #pragma unroll
                    for (int jj = 0; jj < 32; jj++) {
                        float v = sh.g.tile[rr2][h * 32 + jj];
                        ps += v * sh.g.as[h * 32 + jj];
                        pd += v * sh.g.ad[h * 32 + jj];
                    }
                    a_src[(size_t)(r0 + rr2) * 4 + h] = ps;
                    a_dst[(size_t)(r0 + rr2) * 4 + h] = pd;
                }
            }
        }
        return;
    }

    // ---------------- lstm path (16 blocks, division-free nonlinearity)
    int chunk = bid;
    int j = w * 16 + l15;
    int rowq = (lane >> 4) * 4;
    bf16x8 whh_f[4][4];
    #pragma unroll
    for (int c = 0; c < 4; c++) {
        int col = c * 128 + j;
        #pragma unroll
        for (int kk = 0; kk < 4; kk++) {
            const float* wr = &Whh[(size_t)col * 128 + kk * 32 + kq8];
            whh_f[c][kk] = pack8(*reinterpret_cast<const float4*>(wr),
                                 *reinterpret_cast<const float4*>(wr + 4));
        }
    }
    for (int p = t; p < 16 * 148; p += 512) {
        int r = p / 148, cc = p - r * 148;
        sh.l.h16[0][r][cc] = 0;
    }
    float cst[4] = {0.f, 0.f, 0.f, 0.f};
    const float* xb = xproj + ((size_t)chunk * KT) * 32 * 256;
    f32x4 xgA = *reinterpret_cast<const f32x4*>(&xb[(0 * 8 + w) * 256 + lane * 4]);
    f32x4 xgB = *reinterpret_cast<const f32x4*>(&xb[(1 * 8 + w) * 256 + lane * 4]);
    f32x4 xgC = *reinterpret_cast<const f32x4*>(&xb[(2 * 8 + w) * 256 + lane * 4]);
    f32x4 xgD = *reinterpret_cast<const f32x4*>(&xb[(3 * 8 + w) * 256 + lane * 4]);
    int cur = 0;
    __syncthreads();
    for (int s = 0; s < KT; s++) {
        f32x4 nA, nB, nC, nD;
        if (s + 1 < KT) {
            const float* xs = &xb[((size_t)(s + 1) * 32 + w) * 256 + lane * 4];
            nA = *reinterpret_cast<const f32x4*>(&xs[0 * 8 * 256]);
            nB = *reinterpret_cast<const f32x4*>(&xs[1 * 8 * 256]);
            nC = *reinterpret_cast<const f32x4*>(&xs[2 * 8 * 256]);
            nD = *reinterpret_cast<const f32x4*>(&xs[3 * 8 * 256]);
        }
        f32x4 ai = xgA, af = xgB, ag = xgC, ao = xgD;
        #pragma unroll
        for (int kk = 0; kk < 4; kk++) {
            bf16x8 ah = *reinterpret_cast<const bf16x8*>(&sh.l.h16[cur][l15][kk * 32 + kq8]);
            ai = __builtin_amdgcn_mfma_f32_16x16x32_bf16(ah, whh_f[0][kk], ai, 0, 0, 0);
            af = __builtin_amdgcn_mfma_f32_16x16x32_bf16(ah, whh_f[1][kk], af, 0, 0, 0);
            ag = __builtin_amdgcn_mfma_f32_16x16x32_bf16(ah, whh_f[2][kk], ag, 0, 0, 0);
            ao = __builtin_amdgcn_mfma_f32_16x16x32_bf16(ah, whh_f[3][kk], ao, 0, 0, 0);
        }
        int nxt = cur ^ 1;
        #pragma unroll
        for (int r = 0; r < 4; r++) {
            float eiv = __expf(fminf(-ai[r], 25.f));
            float efv = __expf(fminf(-af[r], 25.f));
            float egv = __expf(fminf(2.f * ag[r], 50.f));
            float eov = __expf(fminf(-ao[r], 25.f));
            float pi = 1.f + eiv, pf = 1.f + efv;
            float gp = egv + 1.f, gm = egv - 1.f;
            float P  = pi * gp;
            float D  = pf * P;
            float cn = fmaf(cst[r], P, gm * pf) * __builtin_amdgcn_rcpf(D);
            cst[r] = cn;
            float ecv = __expf(fminf(2.f * cn, 50.f));
            float D2  = (1.f + eov) * (ecv + 1.f);
            float hv  = (ecv - 1.f) * __builtin_amdgcn_rcpf(D2);
            sh.l.h16[nxt][rowq + r][j] = bf1(hv);
        }
        xgA = nA; xgB = nB; xgC = nC; xgD = nD;
        __syncthreads();
        cur = nxt;
    }
    int b0 = chunk * 16;
    for (int p = t; p < 16 * KLH; p += 512) {
        int row = p >> 7, jj = p & 127;
        hstate[(size_t)(b0 + row) * KLH + jj] =
            __uint_as_float((unsigned)sh.l.h16[cur][row][jj] << 16);
    }
}

// ----------------------------------------------------------------- launcher
extern "C" void kernel_launch(void* const* d_in, const int* in_sizes, int n_in,
                              void* d_out, int out_size, void* d_ws, size_t ws_size,
                              hipStream_t stream) {
    const float* x     = (const float*)d_in[0];
    const int*   ei    = (const int*)  d_in[1];
    const int*   batch = (const int*)  d_in[2];
    const float* quant = (const float*)d_in[3];
    const float* gatW  = (const float*)d_in[4];
    const float* attS  = (const float*)d_in[5];
    const float* attD  = (const float*)d_in[6];
    const float* gatB  = (const float*)d_in[7];
    const float* bn1g  = (const float*)d_in[8];
    const float* bn1b  = (const float*)d_in[9];
    const float* bn1m  = (const float*)d_in[10];
    const float* bn1v  = (const float*)d_in[11];
    const float* gcnW  = (const float*)d_in[12];
    const float* gcnB  = (const float*)d_in[13];
    const float* bn2g  = (const float*)d_in[14];
    const float* bn2b  = (const float*)d_in[15];
    const float* bn2m  = (const float*)d_in[16];
    const float* bn2v  = (const float*)d_in[17];
    const float* gateW = (const float*)d_in[18];
    const float* gateB = (const float*)d_in[19];
    const float* Wih   = (const float*)d_in[20];
    const float* Whh   = (const float*)d_in[21];
    const float* bih   = (const float*)d_in[22];
    const float* bhh   = (const float*)d_in[23];
    const float* fcW   = (const float*)d_in[24];
    const float* fcB   = (const float*)d_in[25];

    int N = in_sizes[0] / KIN;
    int E = in_sizes[1] / 2;
    int B = in_sizes[3] / (KT * KQD);
    int nchunks = B / 16;

    char* ws = (char*)d_ws;
    size_t off = 0;
    auto alloc = [&](size_t bytes) -> void* {
        void* p = ws + off;
        off += (bytes + 511) & ~(size_t)511;
        return p;
    };
    int nb = (N + 4095) / 4096;
    int*      deg     = (int*)     alloc((size_t)N * 4);
    int*      offsets = (int*)     alloc((size_t)(N + 1) * 4);
    int*      cursor  = (int*)     alloc((size_t)N * 4);
    float*    dinv    = (float*)   alloc((size_t)N * 4);
    int*      csr_src = (int*)     alloc((size_t)E * 4);
    int*      bsum    = (int*)     alloc((size_t)nb * 4);
    float*    a_src   = (float*)   alloc((size_t)N * 16);
    float*    a_dst   = (float*)   alloc((size_t)N * 16);
    unsigned* xwb     = (unsigned*)alloc((size_t)N * 256);
    float*    hbuf    = (float*)   alloc((size_t)N * 512);
    float*    gate    = (float*)   alloc((size_t)N * 4);
    float*    hstate  = (float*)   alloc((size_t)B * KLH * 4);
    float*    xproj   = (float*)   alloc((size_t)nchunks * KT * 32 * 256 * 4);

    hipMemsetAsync(deg, 0, (size_t)N * 4, stream);
    int eb = (E + 255) / 256;
    k_deg   <<<eb, 256, 0, stream>>>(ei, E, deg);
    k_scan_a<<<nb, 1024, 0, stream>>>(deg, N, bsum);
    k_scan_b<<<1, 64, 0, stream>>>(bsum, nb);
    k_scan_c<<<nb, 1024, 0, stream>>>(deg, N, bsum, offsets, cursor, dinv);

    k_xproj<<<nchunks * KT, 256, 0, stream>>>(quant, Wih, bih, bhh, xproj);

    int ngemm = 1024;
    int nfill = (E + 511) / 512;
    k_fused<<<nchunks + ngemm + nfill, 512, 0, stream>>>(
        xproj, Whh, hstate, nchunks,
        x, gatW, xwb, N, attS, attD, a_src, a_dst, ngemm,
        ei, E, cursor, csr_src);

    k_gat_agg<<<3072, 256, 0, stream>>>(offsets, csr_src, a_src, a_dst, xwb, gatB,
                                        bn1g, bn1b, bn1m, bn1v, hbuf, N);
    k_gemm_mfma<false><<<1024, 256, 0, stream>>>(hbuf, gcnW, xwb, N,
                                                 nullptr, nullptr, nullptr, nullptr);
    k_gcn_agg<<<3072, 256, 0, stream>>>(offsets, csr_src, dinv, xwb, gcnB,
                                        bn2g, bn2b, bn2m, bn2v, gateW, gateB,
                                        hbuf, gate, N);
    k_pool<<<B, 256, 0, stream>>>(batch, gate, hbuf, hstate, fcW, fcB,
                                  (float*)d_out, N);
}